// Round 1
// baseline (1236.741 us; speedup 1.0000x reference)
//
#include <hip/hip_runtime.h>

typedef unsigned short u16;
typedef __attribute__((ext_vector_type(8))) short short8;
typedef __attribute__((ext_vector_type(4))) float f32x4;

#define NROWS   4096     // B*S
#define S_LEN   2048
#define NHEADS  24
#define DMODEL  3072
#define QPROJ   1536
#define KVPROJ  2048
#define CKV_W   2112     // KVPROJ + 64 rope
#define UKV_N   4608     // DMODEL + 24*64

__device__ __forceinline__ float bf2f(u16 v) {
    unsigned u = ((unsigned)v) << 16; float f; __builtin_memcpy(&f, &u, 4); return f;
}
__device__ __forceinline__ u16 f2bf(float f) {
    unsigned u; __builtin_memcpy(&u, &f, 4);
    u = (u + 0x7FFFu + ((u >> 16) & 1u)) >> 16; return (u16)u;
}

// ---------------- elementwise convert fp32 -> bf16 (vectorized) -------------
__global__ void conv_bf16(const float* __restrict__ X, u16* __restrict__ Y, int n) {
    int i = (blockIdx.x * 256 + threadIdx.x) * 4;
    if (i >= n) return;
    float4 v = *(const float4*)(X + i);
    Y[i+0] = f2bf(v.x); Y[i+1] = f2bf(v.y); Y[i+2] = f2bf(v.z); Y[i+3] = f2bf(v.w);
}

// ---------------- transpose + convert: W (K x N) -> WT (N x K) bf16 ---------
__global__ void transpose_bf16(const float* __restrict__ W, u16* __restrict__ WT, int K, int N) {
    __shared__ float t[32][33];
    int nb = blockIdx.x * 32, kb = blockIdx.y * 32;
    int c = threadIdx.x & 31, rq = threadIdx.x >> 5;    // 256 thr = 8 row groups
#pragma unroll
    for (int i = 0; i < 4; ++i) {
        int r = rq * 4 + i;
        t[r][c] = W[(size_t)(kb + r) * N + nb + c];
    }
    __syncthreads();
#pragma unroll
    for (int i = 0; i < 4; ++i) {
        int r = rq * 4 + i;
        WT[(size_t)(nb + r) * K + kb + c] = f2bf(t[c][r]);
    }
}

// ---------------- LayerNorm (fp32 in, bf16 out) -----------------------------
__global__ __launch_bounds__(256) void ln_kernel(const float* __restrict__ X, int ldx,
                                                 const float* __restrict__ g,
                                                 const float* __restrict__ b,
                                                 u16* __restrict__ Y, int W) {
    int row = blockIdx.x;
    const float* x = X + (size_t)row * ldx;
    float s = 0.f, s2 = 0.f;
    for (int i = threadIdx.x; i < W; i += 256) { float v = x[i]; s += v; s2 += v * v; }
#pragma unroll
    for (int off = 32; off >= 1; off >>= 1) { s += __shfl_xor(s, off); s2 += __shfl_xor(s2, off); }
    __shared__ float red[8];
    int w = threadIdx.x >> 6;
    if ((threadIdx.x & 63) == 0) { red[w] = s; red[4 + w] = s2; }
    __syncthreads();
    s  = red[0] + red[1] + red[2] + red[3];
    s2 = red[4] + red[5] + red[6] + red[7];
    float mean = s / W;
    float var  = s2 / W - mean * mean;
    float rstd = rsqrtf(var + 1e-5f);
    u16* y = Y + (size_t)row * W;
    for (int i = threadIdx.x; i < W; i += 256)
        y[i] = f2bf((x[i] - mean) * rstd * g[i] + b[i]);
}

// ---------------- RoPE on Q (in place, bf16) --------------------------------
__global__ void rope_q_kernel(u16* __restrict__ Q) {
    int idx = blockIdx.x * 256 + threadIdx.x;       // NROWS*24*32
    int j = idx & 31; int t = idx >> 5; int h = t % NHEADS; int row = t / NHEADS;
    int s = row & (S_LEN - 1);
    float freq = __expf(-(float)j * (9.210340371976184f / 64.f)); // 10000^(-j/64)
    float ang = (float)s * freq;
    float c = cosf(ang), si = sinf(ang);
    u16* p = Q + (size_t)row * DMODEL + h * 128 + 64;
    float x1 = bf2f(p[j]), x2 = bf2f(p[j + 32]);
    p[j]      = f2bf(x1 * c - x2 * si);
    p[j + 32] = f2bf(x2 * c + x1 * si);
}

// ---------------- RoPE on K_rope (from fp32 ckv -> bf16 kr) -----------------
__global__ void rope_k_kernel(const float* __restrict__ ckv, u16* __restrict__ kr) {
    int idx = blockIdx.x * 256 + threadIdx.x;       // NROWS*32
    int j = idx & 31; int row = idx >> 5;
    int s = row & (S_LEN - 1);
    float freq = __expf(-(float)j * (9.210340371976184f / 64.f));
    float ang = (float)s * freq;
    float c = cosf(ang), si = sinf(ang);
    const float* src = ckv + (size_t)row * CKV_W + KVPROJ;
    float x1 = src[j], x2 = src[j + 32];
    kr[(size_t)row * 64 + j]      = f2bf(x1 * c - x2 * si);
    kr[(size_t)row * 64 + j + 32] = f2bf(x2 * c + x1 * si);
}

// ---------------- GEMM: C[M,N] = A[M,K] * BT[N,K]^T  (bf16 in, fp32/bf16 out)
template<bool OUT_BF16>
__global__ __launch_bounds__(256) void gemm_nt(const u16* __restrict__ A,
                                               const u16* __restrict__ B,
                                               void* __restrict__ Cv,
                                               int M, int N, int K) {
    __shared__ u16 a_lds[128][40];
    __shared__ u16 b_lds[128][40];
    int m0 = blockIdx.y * 128, n0 = blockIdx.x * 128;
    int tid = threadIdx.x, lane = tid & 63, w = tid >> 6;
    int wm = w >> 1, wn = w & 1;
    f32x4 acc[4][4] = {};
    for (int kb = 0; kb < K; kb += 32) {
#pragma unroll
        for (int it = 0; it < 2; ++it) {
            int u = tid + it * 256;              // 0..511
            int row = u >> 2, col = (u & 3) * 8;
            *(uint4*)&a_lds[row][col] = *(const uint4*)&A[(size_t)(m0 + row) * K + kb + col];
            uint4 bv = {0u, 0u, 0u, 0u};
            if (n0 + row < N) bv = *(const uint4*)&B[(size_t)(n0 + row) * K + kb + col];
            *(uint4*)&b_lds[row][col] = bv;
        }
        __syncthreads();
        short8 af[4], bf[4];
#pragma unroll
        for (int i = 0; i < 4; ++i) {
            af[i] = *(const short8*)&a_lds[wm * 64 + i * 16 + (lane & 15)][(lane >> 4) * 8];
            bf[i] = *(const short8*)&b_lds[wn * 64 + i * 16 + (lane & 15)][(lane >> 4) * 8];
        }
#pragma unroll
        for (int i = 0; i < 4; ++i)
#pragma unroll
            for (int j = 0; j < 4; ++j)
                acc[i][j] = __builtin_amdgcn_mfma_f32_16x16x32_bf16(af[i], bf[j], acc[i][j], 0, 0, 0);
        __syncthreads();
    }
#pragma unroll
    for (int i = 0; i < 4; ++i) {
        int row = m0 + wm * 64 + i * 16 + ((lane >> 4) << 2);
#pragma unroll
        for (int j = 0; j < 4; ++j) {
            int col = n0 + wn * 64 + j * 16 + (lane & 15);
            if (col < N) {
#pragma unroll
                for (int r = 0; r < 4; ++r) {
                    if (OUT_BF16) ((u16*)Cv)[(size_t)(row + r) * N + col] = f2bf(acc[i][j][r]);
                    else          ((float*)Cv)[(size_t)(row + r) * N + col] = acc[i][j][r];
                }
            }
        }
    }
}

// ---------------- Flash attention -------------------------------------------
// grid: (S/64, B*H). block 256 (4 waves, 16 q-rows each).
__global__ __launch_bounds__(256) void attn_kernel(const u16* __restrict__ Qb,
                                                   const u16* __restrict__ KVb,
                                                   const u16* __restrict__ Kr,
                                                   u16* __restrict__ AO) {
    __shared__ u16 k_lds[64][136];
    __shared__ u16 vT[128][72];
    __shared__ u16 p_lds[4][16][72];
    int q0 = blockIdx.x * 64;
    int bh = blockIdx.y; int bb = bh / NHEADS, h = bh % NHEADS;
    int tid = threadIdx.x, lane = tid & 63, w = tid >> 6;
    size_t base = (size_t)bb * S_LEN;

    // Q fragments for this wave's 16 rows (stay in registers)
    short8 qf[4];
    {
        int qrow = q0 + w * 16 + (lane & 15);
        const u16* qp = Qb + (base + qrow) * DMODEL + h * 128 + ((lane >> 4) * 8);
#pragma unroll
        for (int ks = 0; ks < 4; ++ks) qf[ks] = *(const short8*)(qp + ks * 32);
    }

    f32x4 acc_o[8] = {};
    float m_run[4], l_run[4];
#pragma unroll
    for (int r = 0; r < 4; ++r) { m_run[r] = -1e30f; l_run[r] = 0.f; }

    int ntiles = blockIdx.x + 1;
    for (int t = 0; t < ntiles; ++t) {
        int kv0 = t * 64;
        // stage K (nope | roped rope) -> k_lds[kv][128]
#pragma unroll
        for (int it = 0; it < 4; ++it) {
            int u = tid + it * 256;             // 0..1023
            int r = u >> 4, cb = u & 15;
            const u16* src = (cb < 8)
                ? KVb + (base + kv0 + r) * UKV_N + h * 192 + cb * 8
                : Kr + (base + kv0 + r) * 64 + (cb - 8) * 8;
            *(uint4*)&k_lds[r][cb * 8] = *(const uint4*)src;
        }
        // stage V transposed -> vT[d][kv]
#pragma unroll
        for (int it = 0; it < 4; ++it) {
            int u = tid + it * 256;
            int r = u >> 4, cb = u & 15;
            uint4 v = *(const uint4*)(KVb + (base + kv0 + r) * UKV_N + h * 192 + 64 + cb * 8);
            u16* vv = (u16*)&v;
#pragma unroll
            for (int e = 0; e < 8; ++e) vT[cb * 8 + e][r] = vv[e];
        }
        __syncthreads();

        // QK^T: 16x64 scores per wave
        f32x4 sc[4];
#pragma unroll
        for (int nb = 0; nb < 4; ++nb) {
            f32x4 a = {};
#pragma unroll
            for (int ks = 0; ks < 4; ++ks) {
                short8 kf = *(const short8*)&k_lds[nb * 16 + (lane & 15)][ks * 32 + (lane >> 4) * 8];
                a = __builtin_amdgcn_mfma_f32_16x16x32_bf16(qf[ks], kf, a, 0, 0, 0);
            }
            sc[nb] = a;
        }

        const float scale = 0.08838834764831845f;
        int qg = q0 + w * 16 + ((lane >> 4) << 2);
#pragma unroll
        for (int nb = 0; nb < 4; ++nb) {
            int kc = kv0 + nb * 16 + (lane & 15);
#pragma unroll
            for (int r = 0; r < 4; ++r) {
                float v = sc[nb][r] * scale;
                if (kc > qg + r) v = -1e30f;
                sc[nb][r] = v;
            }
        }
        // row max over 4 frags + 16 lanes of the row group
        float rmax[4];
#pragma unroll
        for (int r = 0; r < 4; ++r)
            rmax[r] = fmaxf(fmaxf(sc[0][r], sc[1][r]), fmaxf(sc[2][r], sc[3][r]));
#pragma unroll
        for (int off = 1; off < 16; off <<= 1)
#pragma unroll
            for (int r = 0; r < 4; ++r) rmax[r] = fmaxf(rmax[r], __shfl_xor(rmax[r], off));

        float mnew[4], fac[4], rsum[4];
#pragma unroll
        for (int r = 0; r < 4; ++r) {
            mnew[r] = fmaxf(m_run[r], rmax[r]);
            fac[r] = __expf(m_run[r] - mnew[r]);
            rsum[r] = 0.f;
        }
#pragma unroll
        for (int nb = 0; nb < 4; ++nb)
#pragma unroll
            for (int r = 0; r < 4; ++r) {
                float p = __expf(sc[nb][r] - mnew[r]);
                sc[nb][r] = p; rsum[r] += p;
            }
#pragma unroll
        for (int off = 1; off < 16; off <<= 1)
#pragma unroll
            for (int r = 0; r < 4; ++r) rsum[r] += __shfl_xor(rsum[r], off);
#pragma unroll
        for (int r = 0; r < 4; ++r) {
            l_run[r] = l_run[r] * fac[r] + rsum[r];
            m_run[r] = mnew[r];
        }
#pragma unroll
        for (int db = 0; db < 8; ++db)
#pragma unroll
            for (int r = 0; r < 4; ++r) acc_o[db][r] *= fac[r];

        // write P (bf16) into per-wave LDS, then PV
#pragma unroll
        for (int nb = 0; nb < 4; ++nb)
#pragma unroll
            for (int r = 0; r < 4; ++r)
                p_lds[w][((lane >> 4) << 2) + r][nb * 16 + (lane & 15)] = f2bf(sc[nb][r]);
        __builtin_amdgcn_sched_barrier(0);
#pragma unroll
        for (int ks = 0; ks < 2; ++ks) {
            short8 pf = *(const short8*)&p_lds[w][lane & 15][ks * 32 + (lane >> 4) * 8];
#pragma unroll
            for (int db = 0; db < 8; ++db) {
                short8 vf = *(const short8*)&vT[db * 16 + (lane & 15)][ks * 32 + (lane >> 4) * 8];
                acc_o[db] = __builtin_amdgcn_mfma_f32_16x16x32_bf16(pf, vf, acc_o[db], 0, 0, 0);
            }
        }
        __syncthreads();
    }

    int orow = q0 + w * 16 + ((lane >> 4) << 2);
#pragma unroll
    for (int db = 0; db < 8; ++db)
#pragma unroll
        for (int r = 0; r < 4; ++r) {
            float o = acc_o[db][r] / l_run[r];
            AO[(base + orow + r) * DMODEL + h * 128 + db * 16 + (lane & 15)] = f2bf(o);
        }
}

// ---------------------------------------------------------------------------
extern "C" void kernel_launch(void* const* d_in, const int* in_sizes, int n_in,
                              void* d_out, int out_size, void* d_ws, size_t ws_size,
                              hipStream_t stream) {
    (void)in_sizes; (void)n_in; (void)out_size; (void)ws_size;
    const float* x      = (const float*)d_in[0];
    const float* W_dq   = (const float*)d_in[1];
    const float* W_uq   = (const float*)d_in[2];
    const float* q_ln_w = (const float*)d_in[3];
    const float* q_ln_b = (const float*)d_in[4];
    const float* W_dkv  = (const float*)d_in[5];
    const float* W_ukv  = (const float*)d_in[6];
    const float* kv_ln_w= (const float*)d_in[7];
    const float* kv_ln_b= (const float*)d_in[8];
    const float* W_o    = (const float*)d_in[9];

    float* out = (float*)d_out;
    float* ckv = out + (size_t)NROWS * DMODEL;   // output #2 region

    char* ws = (char*)d_ws;
    const size_t OFF_WDQT  = 0;
    const size_t OFF_WUQT  = 9437184;
    const size_t OFF_WDKVT = 18874368;
    const size_t OFF_WUKVT = 31850496;
    const size_t OFF_WO    = 50724864;
    const size_t OFF_XB    = 69599232;
    const size_t OFF_QB    = 94765056;
    const size_t OFF_KVB   = 119930880;
    const size_t OFF_KR    = 157679616;
    const size_t OFF_SLABA = 158203904;  // t0 fp32, later ao bf16
    const size_t OFF_SLABB = 183369728;  // cq bf16, later kvl bf16

    u16* Wdq_t  = (u16*)(ws + OFF_WDQT);
    u16* Wuq_t  = (u16*)(ws + OFF_WUQT);
    u16* Wdkv_t = (u16*)(ws + OFF_WDKVT);
    u16* Wukv_t = (u16*)(ws + OFF_WUKVT);
    u16* Wo_b   = (u16*)(ws + OFF_WO);
    u16* xb     = (u16*)(ws + OFF_XB);
    u16* qb     = (u16*)(ws + OFF_QB);
    u16* KVb    = (u16*)(ws + OFF_KVB);
    u16* kr     = (u16*)(ws + OFF_KR);
    float* t0   = (float*)(ws + OFF_SLABA);
    u16* ao     = (u16*)(ws + OFF_SLABA);
    u16* cq     = (u16*)(ws + OFF_SLABB);
    u16* kvl    = (u16*)(ws + OFF_SLABB);

    // weight prep
    transpose_bf16<<<dim3(QPROJ / 32, DMODEL / 32), 256, 0, stream>>>(W_dq,  Wdq_t,  DMODEL, QPROJ);
    transpose_bf16<<<dim3(DMODEL / 32, QPROJ / 32), 256, 0, stream>>>(W_uq,  Wuq_t,  QPROJ, DMODEL);
    transpose_bf16<<<dim3(CKV_W / 32, DMODEL / 32), 256, 0, stream>>>(W_dkv, Wdkv_t, DMODEL, CKV_W);
    transpose_bf16<<<dim3(UKV_N / 32, KVPROJ / 32), 256, 0, stream>>>(W_ukv, Wukv_t, KVPROJ, UKV_N);
    conv_bf16<<<9216, 256, 0, stream>>>(W_o, Wo_b, DMODEL * DMODEL);
    conv_bf16<<<12288, 256, 0, stream>>>(x, xb, NROWS * DMODEL);

    // q path
    gemm_nt<false><<<dim3(QPROJ / 128, NROWS / 128), 256, 0, stream>>>(xb, Wdq_t, t0, NROWS, QPROJ, DMODEL);
    ln_kernel<<<NROWS, 256, 0, stream>>>(t0, QPROJ, q_ln_w, q_ln_b, cq, QPROJ);
    gemm_nt<true><<<dim3(DMODEL / 128, NROWS / 128), 256, 0, stream>>>(cq, Wuq_t, qb, NROWS, DMODEL, QPROJ);
    rope_q_kernel<<<12288, 256, 0, stream>>>(qb);

    // kv path
    gemm_nt<false><<<dim3((CKV_W + 127) / 128, NROWS / 128), 256, 0, stream>>>(xb, Wdkv_t, ckv, NROWS, CKV_W, DMODEL);
    ln_kernel<<<NROWS, 256, 0, stream>>>(ckv, CKV_W, kv_ln_w, kv_ln_b, kvl, KVPROJ);
    rope_k_kernel<<<512, 256, 0, stream>>>(ckv, kr);
    gemm_nt<true><<<dim3(UKV_N / 128, NROWS / 128), 256, 0, stream>>>(kvl, Wukv_t, KVb, NROWS, UKV_N, KVPROJ);

    // attention
    attn_kernel<<<dim3(S_LEN / 64, 2 * NHEADS), 256, 0, stream>>>(qb, KVb, kr, ao);

    // output projection
    gemm_nt<false><<<dim3(DMODEL / 128, NROWS / 128), 256, 0, stream>>>(ao, Wo_b, out, NROWS, DMODEL, DMODEL);
}

// Round 3
// 805.572 us; speedup vs baseline: 1.5352x; 1.5352x over previous
//
#include <hip/hip_runtime.h>

typedef unsigned short u16;
typedef __attribute__((ext_vector_type(8))) short short8;
typedef __attribute__((ext_vector_type(4))) float f32x4;

#define NROWS   4096     // B*S
#define S_LEN   2048
#define NHEADS  24
#define DMODEL  3072
#define QPROJ   1536
#define KVPROJ  2048
#define CKV_W   2112     // KVPROJ + 64 rope
#define UKV_N   4608     // DMODEL + 24*64

__device__ __forceinline__ float bf2f(u16 v) {
    unsigned u = ((unsigned)v) << 16; float f; __builtin_memcpy(&f, &u, 4); return f;
}
__device__ __forceinline__ u16 f2bf(float f) {
    unsigned u; __builtin_memcpy(&u, &f, 4);
    u = (u + 0x7FFFu + ((u >> 16) & 1u)) >> 16; return (u16)u;
}
__device__ __forceinline__ void async16(const u16* g, u16* l) {
    __builtin_amdgcn_global_load_lds((const __attribute__((address_space(1))) unsigned int*)g,
                                     (__attribute__((address_space(3))) unsigned int*)l,
                                     16, 0, 0);
}

// ---------------- elementwise convert fp32 -> bf16 (vectorized) -------------
__global__ void conv_bf16(const float* __restrict__ X, u16* __restrict__ Y, int n) {
    int i = (blockIdx.x * 256 + threadIdx.x) * 4;
    if (i >= n) return;
    float4 v = *(const float4*)(X + i);
    Y[i+0] = f2bf(v.x); Y[i+1] = f2bf(v.y); Y[i+2] = f2bf(v.z); Y[i+3] = f2bf(v.w);
}

// ---------------- transpose + convert: W (K x N) -> WT (N x K) bf16 ---------
__global__ void transpose_bf16(const float* __restrict__ W, u16* __restrict__ WT, int K, int N) {
    __shared__ float t[32][33];
    int nb = blockIdx.x * 32, kb = blockIdx.y * 32;
    int c = threadIdx.x & 31, rq = threadIdx.x >> 5;
#pragma unroll
    for (int i = 0; i < 4; ++i) {
        int r = rq * 4 + i;
        t[r][c] = W[(size_t)(kb + r) * N + nb + c];
    }
    __syncthreads();
#pragma unroll
    for (int i = 0; i < 4; ++i) {
        int r = rq * 4 + i;
        WT[(size_t)(nb + r) * K + kb + c] = f2bf(t[c][r]);
    }
}

// ---------------- LayerNorm (fp32 in, bf16 out) -----------------------------
__global__ __launch_bounds__(256) void ln_kernel(const float* __restrict__ X, int ldx,
                                                 const float* __restrict__ g,
                                                 const float* __restrict__ b,
                                                 u16* __restrict__ Y, int W) {
    int row = blockIdx.x;
    const float* x = X + (size_t)row * ldx;
    float s = 0.f, s2 = 0.f;
    for (int i = threadIdx.x; i < W; i += 256) { float v = x[i]; s += v; s2 += v * v; }
#pragma unroll
    for (int off = 32; off >= 1; off >>= 1) { s += __shfl_xor(s, off); s2 += __shfl_xor(s2, off); }
    __shared__ float red[8];
    int w = threadIdx.x >> 6;
    if ((threadIdx.x & 63) == 0) { red[w] = s; red[4 + w] = s2; }
    __syncthreads();
    s  = red[0] + red[1] + red[2] + red[3];
    s2 = red[4] + red[5] + red[6] + red[7];
    float mean = s / W;
    float var  = s2 / W - mean * mean;
    float rstd = rsqrtf(var + 1e-5f);
    u16* y = Y + (size_t)row * W;
    for (int i = threadIdx.x; i < W; i += 256)
        y[i] = f2bf((x[i] - mean) * rstd * g[i] + b[i]);
}

// ---------------- RoPE on Q (in place, bf16) --------------------------------
__global__ void rope_q_kernel(u16* __restrict__ Q) {
    int idx = blockIdx.x * 256 + threadIdx.x;       // NROWS*24*32
    int j = idx & 31; int t = idx >> 5; int h = t % NHEADS; int row = t / NHEADS;
    int s = row & (S_LEN - 1);
    float freq = __expf(-(float)j * (9.210340371976184f / 64.f)); // 10000^(-j/64)
    float ang = (float)s * freq;
    float c = cosf(ang), si = sinf(ang);
    u16* p = Q + (size_t)row * DMODEL + h * 128 + 64;
    float x1 = bf2f(p[j]), x2 = bf2f(p[j + 32]);
    p[j]      = f2bf(x1 * c - x2 * si);
    p[j + 32] = f2bf(x2 * c + x1 * si);
}

// ---------------- RoPE on K_rope (from fp32 ckv -> bf16 kr) -----------------
__global__ void rope_k_kernel(const float* __restrict__ ckv, u16* __restrict__ kr) {
    int idx = blockIdx.x * 256 + threadIdx.x;       // NROWS*32
    int j = idx & 31; int row = idx >> 5;
    int s = row & (S_LEN - 1);
    float freq = __expf(-(float)j * (9.210340371976184f / 64.f));
    float ang = (float)s * freq;
    float c = cosf(ang), si = sinf(ang);
    const float* src = ckv + (size_t)row * CKV_W + KVPROJ;
    float x1 = src[j], x2 = src[j + 32];
    kr[(size_t)row * 64 + j]      = f2bf(x1 * c - x2 * si);
    kr[(size_t)row * 64 + j + 32] = f2bf(x2 * c + x1 * si);
}

// ---------------- pack K: Kp[bh][s][128] = nope | roped rope ----------------
__global__ __launch_bounds__(256) void pack_k(const u16* __restrict__ KVb,
                                              const u16* __restrict__ kr,
                                              u16* __restrict__ Kp) {
    int bh = blockIdx.y, bb = bh / NHEADS, h = bh % NHEADS;
    int s0 = blockIdx.x * 64;
    int t = threadIdx.x;
    size_t base = (size_t)bb * S_LEN;
#pragma unroll
    for (int it = 0; it < 4; ++it) {
        int j = it * 256 + t;
        int r = j >> 4, cb = (j & 15) * 8;
        int s = s0 + r;
        uint4 v;
        if (cb < 64) v = *(const uint4*)&KVb[(base + s) * UKV_N + h * 192 + cb];
        else         v = *(const uint4*)&kr[(base + s) * 64 + (cb - 64)];
        *(uint4*)&Kp[((size_t)bh * S_LEN + s) * 128 + cb] = v;
    }
}

// ---------------- pack V transposed: Vt[bh][d][s] ---------------------------
__global__ __launch_bounds__(256) void pack_v(const u16* __restrict__ KVb,
                                              u16* __restrict__ Vt) {
    __shared__ u16 tile[64][136];
    int bh = blockIdx.y, bb = bh / NHEADS, h = bh % NHEADS;
    int s0 = blockIdx.x * 64;
    int t = threadIdx.x;
    size_t base = (size_t)bb * S_LEN;
#pragma unroll
    for (int it = 0; it < 4; ++it) {
        int j = it * 256 + t;
        int r = j >> 4, cb = (j & 15) * 8;
        *(uint4*)&tile[r][cb] = *(const uint4*)&KVb[(base + s0 + r) * UKV_N + h * 192 + 64 + cb];
    }
    __syncthreads();
#pragma unroll
    for (int it = 0; it < 4; ++it) {
        int j = it * 256 + t;
        int d = j >> 3, sb = (j & 7) * 8;
        u16 tmp[8];
#pragma unroll
        for (int e = 0; e < 8; ++e) tmp[e] = tile[sb + e][d];
        *(uint4*)&Vt[((size_t)bh * 128 + d) * S_LEN + s0 + sb] = *(uint4*)tmp;
    }
}

// ---------------- GEMM (m97 structure): C[M,N] = A[M,K] * B[N,K]^T ----------
template<bool OUT_BF16>
__global__ __launch_bounds__(256) void gemm_nt(const u16* __restrict__ A,
                                               const u16* __restrict__ B,
                                               void* __restrict__ Cv,
                                               int M, int N, int K) {
    __shared__ u16 a_lds[128][32];
    __shared__ u16 b_lds[128][32];
    int m0 = blockIdx.y * 128, n0 = blockIdx.x * 128;
    int tid = threadIdx.x, lane = tid & 63, w = tid >> 6;
    int wm = w >> 1, wn = w & 1;
    int srow = lane >> 2, scol = (lane & 3) * 8;
    int r0 = (w * 2 + 0) * 16 + srow, r1 = (w * 2 + 1) * 16 + srow;
    const u16* A0 = A + (size_t)(m0 + r0) * K + scol;
    const u16* A1 = A + (size_t)(m0 + r1) * K + scol;
    int bn0 = n0 + r0; if (bn0 >= N) bn0 = N - 1;
    int bn1 = n0 + r1; if (bn1 >= N) bn1 = N - 1;
    const u16* B0 = B + (size_t)bn0 * K + scol;
    const u16* B1 = B + (size_t)bn1 * K + scol;
    u16* la0 = &a_lds[(w * 2 + 0) * 16][0];
    u16* la1 = &a_lds[(w * 2 + 1) * 16][0];
    u16* lb0 = &b_lds[(w * 2 + 0) * 16][0];
    u16* lb1 = &b_lds[(w * 2 + 1) * 16][0];
    f32x4 acc[4][4] = {};
    for (int kb = 0; kb < K; kb += 32) {
        async16(A0 + kb, la0);
        async16(A1 + kb, la1);
        async16(B0 + kb, lb0);
        async16(B1 + kb, lb1);
        __syncthreads();
        short8 af[4], bf[4];
#pragma unroll
        for (int i = 0; i < 4; ++i) {
            af[i] = *(const short8*)&a_lds[wm * 64 + i * 16 + (lane & 15)][(lane >> 4) * 8];
            bf[i] = *(const short8*)&b_lds[wn * 64 + i * 16 + (lane & 15)][(lane >> 4) * 8];
        }
#pragma unroll
        for (int i = 0; i < 4; ++i)
#pragma unroll
            for (int j = 0; j < 4; ++j)
                acc[i][j] = __builtin_amdgcn_mfma_f32_16x16x32_bf16(af[i], bf[j], acc[i][j], 0, 0, 0);
        __syncthreads();
    }
#pragma unroll
    for (int i = 0; i < 4; ++i) {
        int row = m0 + wm * 64 + i * 16 + ((lane >> 4) << 2);
#pragma unroll
        for (int j = 0; j < 4; ++j) {
            int col = n0 + wn * 64 + j * 16 + (lane & 15);
            if (col < N) {
#pragma unroll
                for (int r = 0; r < 4; ++r) {
                    if (OUT_BF16) ((u16*)Cv)[(size_t)(row + r) * N + col] = f2bf(acc[i][j][r]);
                    else          ((float*)Cv)[(size_t)(row + r) * N + col] = acc[i][j][r];
                }
            }
        }
    }
}

// ---------------- Flash attention -------------------------------------------
// grid: (S/64, B*H). block 256 (4 waves, 16 q-rows each).
// Kp[bh][s][128], Vt[bh][d][2048]; staged via global_load_lds with XOR-swizzled
// per-lane SOURCE addresses (data linear in global), reads XOR-matched.
__global__ __launch_bounds__(256) void attn_kernel(const u16* __restrict__ Qb,
                                                   const u16* __restrict__ Kp,
                                                   const u16* __restrict__ Vt,
                                                   u16* __restrict__ AO) {
    __shared__ u16 k_lds[64][128];
    __shared__ u16 v_lds[128][64];
    __shared__ u16 p_lds[4][16][72];
    int qx = (int)gridDim.x - 1 - (int)blockIdx.x;   // longest blocks first
    int q0 = qx * 64;
    int bh = blockIdx.y; int bb = bh / NHEADS, h = bh % NHEADS;
    int tid = threadIdx.x, lane = tid & 63, w = tid >> 6;
    size_t base = (size_t)bb * S_LEN;
    size_t bhS = (size_t)bh * S_LEN;

    // Q fragments (registers)
    short8 qf[4];
    {
        int qrow = q0 + w * 16 + (lane & 15);
        const u16* qp = Qb + (base + qrow) * DMODEL + h * 128 + ((lane >> 4) * 8);
#pragma unroll
        for (int ks = 0; ks < 4; ++ks) qf[ks] = *(const short8*)(qp + ks * 32);
    }

    // precomputed staging addresses (byte offsets); per tile add kv0-dependent part
    // k_lds row = 256B = 16 chunks; v_lds row = 128B = 8 chunks. Chunk j of the
    // linear gload_lds stream lands at byte j*16; source picks the inverse-
    // swizzled global chunk so that reads XOR-matched by (row&7) are conflict-free.
    const char* Kbyte = (const char*)Kp;
    const char* Vbyte = (const char*)Vt;
    size_t ksrc[4], vsrc[4];
    u16 *kdst[4], *vdst[4];
#pragma unroll
    for (int is = 0; is < 4; ++is) {
        int j = is * 256 + tid;
        int r = j >> 4;
        int cbs = ((j & 15) * 16) ^ ((r & 7) << 4);
        ksrc[is] = (bhS + r) * 256 + cbs;
        kdst[is] = (u16*)((char*)&k_lds[0][0] + (size_t)(is * 256 + w * 64) * 16);
        int d = j >> 3;
        int kbs = (((j & 7) ^ (d & 7)) * 16);
        vsrc[is] = ((size_t)bh * 128 + d) * (S_LEN * 2) + kbs;
        vdst[is] = (u16*)((char*)&v_lds[0][0] + (size_t)(is * 256 + w * 64) * 16);
    }

    f32x4 acc_o[8] = {};
    float m_run[4], l_run[4];
#pragma unroll
    for (int r = 0; r < 4; ++r) { m_run[r] = -1e30f; l_run[r] = 0.f; }

    int ntiles = qx + 1;
    for (int t = 0; t < ntiles; ++t) {
        int kv0 = t * 64;
#pragma unroll
        for (int is = 0; is < 4; ++is)
            async16((const u16*)(Kbyte + ksrc[is] + (size_t)kv0 * 256), kdst[is]);
#pragma unroll
        for (int is = 0; is < 4; ++is)
            async16((const u16*)(Vbyte + vsrc[is] + (size_t)kv0 * 2), vdst[is]);
        __syncthreads();

        // QK^T: 16x64 scores per wave (swizzled k_lds reads)
        f32x4 sc[4];
#pragma unroll
        for (int nb = 0; nb < 4; ++nb) {
            f32x4 a = {};
            int row = nb * 16 + (lane & 15);
            const char* kb_ = (const char*)&k_lds[0][0] + row * 256;
            int x = (row & 7) << 4;
#pragma unroll
            for (int ks = 0; ks < 4; ++ks) {
                short8 kf = *(const short8*)(kb_ + ((ks * 64 + (lane >> 4) * 16) ^ x));
                a = __builtin_amdgcn_mfma_f32_16x16x32_bf16(qf[ks], kf, a, 0, 0, 0);
            }
            sc[nb] = a;
        }

        const float scale = 0.08838834764831845f;
        int qg = q0 + w * 16 + ((lane >> 4) << 2);
#pragma unroll
        for (int nb = 0; nb < 4; ++nb) {
            int kc = kv0 + nb * 16 + (lane & 15);
#pragma unroll
            for (int r = 0; r < 4; ++r) {
                float v = sc[nb][r] * scale;
                if (kc > qg + r) v = -1e30f;
                sc[nb][r] = v;
            }
        }
        float rmax[4];
#pragma unroll
        for (int r = 0; r < 4; ++r)
            rmax[r] = fmaxf(fmaxf(sc[0][r], sc[1][r]), fmaxf(sc[2][r], sc[3][r]));
#pragma unroll
        for (int off = 1; off < 16; off <<= 1)
#pragma unroll
            for (int r = 0; r < 4; ++r) rmax[r] = fmaxf(rmax[r], __shfl_xor(rmax[r], off));

        float mnew[4], fac[4], rsum[4];
#pragma unroll
        for (int r = 0; r < 4; ++r) {
            mnew[r] = fmaxf(m_run[r], rmax[r]);
            fac[r] = __expf(m_run[r] - mnew[r]);
            rsum[r] = 0.f;
        }
#pragma unroll
        for (int nb = 0; nb < 4; ++nb)
#pragma unroll
            for (int r = 0; r < 4; ++r) {
                float p = __expf(sc[nb][r] - mnew[r]);
                sc[nb][r] = p; rsum[r] += p;
            }
#pragma unroll
        for (int off = 1; off < 16; off <<= 1)
#pragma unroll
            for (int r = 0; r < 4; ++r) rsum[r] += __shfl_xor(rsum[r], off);
#pragma unroll
        for (int r = 0; r < 4; ++r) {
            l_run[r] = l_run[r] * fac[r] + rsum[r];
            m_run[r] = mnew[r];
        }
#pragma unroll
        for (int db = 0; db < 8; ++db)
#pragma unroll
            for (int r = 0; r < 4; ++r) acc_o[db][r] *= fac[r];

        // P -> per-wave LDS (bf16), then PV with swizzled v_lds reads
#pragma unroll
        for (int nb = 0; nb < 4; ++nb)
#pragma unroll
            for (int r = 0; r < 4; ++r)
                p_lds[w][((lane >> 4) << 2) + r][nb * 16 + (lane & 15)] = f2bf(sc[nb][r]);
        __builtin_amdgcn_sched_barrier(0);
#pragma unroll
        for (int ks = 0; ks < 2; ++ks) {
            short8 pf = *(const short8*)&p_lds[w][lane & 15][ks * 32 + (lane >> 4) * 8];
#pragma unroll
            for (int db = 0; db < 8; ++db) {
                int row = db * 16 + (lane & 15);
                const char* vb_ = (const char*)&v_lds[0][0] + row * 128;
                short8 vf = *(const short8*)(vb_ + ((ks * 64 + (lane >> 4) * 16) ^ ((row & 7) << 4)));
                acc_o[db] = __builtin_amdgcn_mfma_f32_16x16x32_bf16(pf, vf, acc_o[db], 0, 0, 0);
            }
        }
        __syncthreads();
    }

    int orow = q0 + w * 16 + ((lane >> 4) << 2);
#pragma unroll
    for (int db = 0; db < 8; ++db)
#pragma unroll
        for (int r = 0; r < 4; ++r) {
            float o = acc_o[db][r] / l_run[r];
            AO[(base + orow + r) * DMODEL + h * 128 + db * 16 + (lane & 15)] = f2bf(o);
        }
}

// ---------------------------------------------------------------------------
extern "C" void kernel_launch(void* const* d_in, const int* in_sizes, int n_in,
                              void* d_out, int out_size, void* d_ws, size_t ws_size,
                              hipStream_t stream) {
    (void)in_sizes; (void)n_in; (void)out_size; (void)ws_size;
    const float* x      = (const float*)d_in[0];
    const float* W_dq   = (const float*)d_in[1];
    const float* W_uq   = (const float*)d_in[2];
    const float* q_ln_w = (const float*)d_in[3];
    const float* q_ln_b = (const float*)d_in[4];
    const float* W_dkv  = (const float*)d_in[5];
    const float* W_ukv  = (const float*)d_in[6];
    const float* kv_ln_w= (const float*)d_in[7];
    const float* kv_ln_b= (const float*)d_in[8];
    const float* W_o    = (const float*)d_in[9];

    float* out = (float*)d_out;
    float* ckv = out + (size_t)NROWS * DMODEL;   // output #2 region

    char* ws = (char*)d_ws;
    const size_t OFF_WDQT  = 0;
    const size_t OFF_WUQT  = 9437184;
    const size_t OFF_WDKVT = 18874368;
    const size_t OFF_WUKVT = 31850496;
    const size_t OFF_WO    = 50724864;
    const size_t OFF_XB    = 69599232;
    const size_t OFF_QB    = 94765056;
    const size_t OFF_KVB   = 119930880;
    const size_t OFF_KR    = 157679616;
    const size_t OFF_SLABA = 158203904;  // t0 fp32, later ao bf16
    const size_t OFF_SLABB = 183369728;  // cq bf16, later kvl bf16
    // reuse of dead regions (after Wukv gemm):
    const size_t OFF_KP    = 0;          // over Wdq_t/Wuq_t/Wdkv_t (dead), 25.2MB
    const size_t OFF_VT    = OFF_XB;     // over xb (dead), 25.2MB

    u16* Wdq_t  = (u16*)(ws + OFF_WDQT);
    u16* Wuq_t  = (u16*)(ws + OFF_WUQT);
    u16* Wdkv_t = (u16*)(ws + OFF_WDKVT);
    u16* Wukv_t = (u16*)(ws + OFF_WUKVT);
    u16* Wo_b   = (u16*)(ws + OFF_WO);
    u16* xb     = (u16*)(ws + OFF_XB);
    u16* qb     = (u16*)(ws + OFF_QB);
    u16* KVb    = (u16*)(ws + OFF_KVB);
    u16* kr     = (u16*)(ws + OFF_KR);
    float* t0   = (float*)(ws + OFF_SLABA);
    u16* ao     = (u16*)(ws + OFF_SLABA);
    u16* cq     = (u16*)(ws + OFF_SLABB);
    u16* kvl    = (u16*)(ws + OFF_SLABB);
    u16* Kp     = (u16*)(ws + OFF_KP);
    u16* Vt     = (u16*)(ws + OFF_VT);

    // weight prep
    transpose_bf16<<<dim3(QPROJ / 32, DMODEL / 32), 256, 0, stream>>>(W_dq,  Wdq_t,  DMODEL, QPROJ);
    transpose_bf16<<<dim3(DMODEL / 32, QPROJ / 32), 256, 0, stream>>>(W_uq,  Wuq_t,  QPROJ, DMODEL);
    transpose_bf16<<<dim3(CKV_W / 32, DMODEL / 32), 256, 0, stream>>>(W_dkv, Wdkv_t, DMODEL, CKV_W);
    transpose_bf16<<<dim3(UKV_N / 32, KVPROJ / 32), 256, 0, stream>>>(W_ukv, Wukv_t, KVPROJ, UKV_N);
    conv_bf16<<<9216, 256, 0, stream>>>(W_o, Wo_b, DMODEL * DMODEL);
    conv_bf16<<<12288, 256, 0, stream>>>(x, xb, NROWS * DMODEL);

    // q path
    gemm_nt<false><<<dim3(QPROJ / 128, NROWS / 128), 256, 0, stream>>>(xb, Wdq_t, t0, NROWS, QPROJ, DMODEL);
    ln_kernel<<<NROWS, 256, 0, stream>>>(t0, QPROJ, q_ln_w, q_ln_b, cq, QPROJ);
    gemm_nt<true><<<dim3(DMODEL / 128, NROWS / 128), 256, 0, stream>>>(cq, Wuq_t, qb, NROWS, DMODEL, QPROJ);
    rope_q_kernel<<<12288, 256, 0, stream>>>(qb);

    // kv path
    gemm_nt<false><<<dim3((CKV_W + 127) / 128, NROWS / 128), 256, 0, stream>>>(xb, Wdkv_t, ckv, NROWS, CKV_W, DMODEL);
    ln_kernel<<<NROWS, 256, 0, stream>>>(ckv, CKV_W, kv_ln_w, kv_ln_b, kvl, KVPROJ);
    rope_k_kernel<<<512, 256, 0, stream>>>(ckv, kr);
    gemm_nt<true><<<dim3(UKV_N / 128, NROWS / 128), 256, 0, stream>>>(kvl, Wukv_t, KVb, NROWS, UKV_N, KVPROJ);

    // pack K/V for attention (Wdq_t/Wuq_t/Wdkv_t and xb are dead now)
    pack_k<<<dim3(S_LEN / 64, 2 * NHEADS), 256, 0, stream>>>(KVb, kr, Kp);
    pack_v<<<dim3(S_LEN / 64, 2 * NHEADS), 256, 0, stream>>>(KVb, Vt);

    // attention
    attn_kernel<<<dim3(S_LEN / 64, 2 * NHEADS), 256, 0, stream>>>(qb, Kp, Vt, ao);

    // output projection
    gemm_nt<false><<<dim3(DMODEL / 128, NROWS / 128), 256, 0, stream>>>(ao, Wo_b, out, NROWS, DMODEL, DMODEL);
}

// Round 4
// 741.996 us; speedup vs baseline: 1.6668x; 1.0857x over previous
//
#include <hip/hip_runtime.h>

typedef unsigned short u16;
typedef __attribute__((ext_vector_type(8))) short short8;
typedef __attribute__((ext_vector_type(4))) float f32x4;

#define NROWS   4096     // B*S
#define S_LEN   2048
#define NHEADS  24
#define DMODEL  3072
#define QPROJ   1536
#define KVPROJ  2048
#define CKV_W   2112     // KVPROJ + 64 rope
#define UKV_N   4608     // DMODEL + 24*64

__device__ __forceinline__ float bf2f(u16 v) {
    unsigned u = ((unsigned)v) << 16; float f; __builtin_memcpy(&f, &u, 4); return f;
}
__device__ __forceinline__ u16 f2bf(float f) {
    unsigned u; __builtin_memcpy(&u, &f, 4);
    u = (u + 0x7FFFu + ((u >> 16) & 1u)) >> 16; return (u16)u;
}
__device__ __forceinline__ void async16(const u16* g, u16* l) {
    __builtin_amdgcn_global_load_lds((const __attribute__((address_space(1))) unsigned int*)g,
                                     (__attribute__((address_space(3))) unsigned int*)l,
                                     16, 0, 0);
}

// ---------------- elementwise convert fp32 -> bf16 (vectorized) -------------
__global__ void conv_bf16(const float* __restrict__ X, u16* __restrict__ Y, int n) {
    int i = (blockIdx.x * 256 + threadIdx.x) * 4;
    if (i >= n) return;
    float4 v = *(const float4*)(X + i);
    Y[i+0] = f2bf(v.x); Y[i+1] = f2bf(v.y); Y[i+2] = f2bf(v.z); Y[i+3] = f2bf(v.w);
}

// ---------------- transpose + convert + scale: W (K x N) -> WT (N x K) bf16 -
__global__ void transpose_bf16(const float* __restrict__ W, u16* __restrict__ WT,
                               int K, int N, float scale) {
    __shared__ float t[32][33];
    int nb = blockIdx.x * 32, kb = blockIdx.y * 32;
    int c = threadIdx.x & 31, rq = threadIdx.x >> 5;
#pragma unroll
    for (int i = 0; i < 4; ++i) {
        int r = rq * 4 + i;
        t[r][c] = W[(size_t)(kb + r) * N + nb + c];
    }
    __syncthreads();
#pragma unroll
    for (int i = 0; i < 4; ++i) {
        int r = rq * 4 + i;
        WT[(size_t)(nb + r) * K + kb + c] = f2bf(t[c][r] * scale);
    }
}

// ---------------- LayerNorm (fp32 in, bf16 out) -----------------------------
__global__ __launch_bounds__(256) void ln_kernel(const float* __restrict__ X, int ldx,
                                                 const float* __restrict__ g,
                                                 const float* __restrict__ b,
                                                 u16* __restrict__ Y, int W) {
    int row = blockIdx.x;
    const float* x = X + (size_t)row * ldx;
    float s = 0.f, s2 = 0.f;
    for (int i = threadIdx.x; i < W; i += 256) { float v = x[i]; s += v; s2 += v * v; }
#pragma unroll
    for (int off = 32; off >= 1; off >>= 1) { s += __shfl_xor(s, off); s2 += __shfl_xor(s2, off); }
    __shared__ float red[8];
    int w = threadIdx.x >> 6;
    if ((threadIdx.x & 63) == 0) { red[w] = s; red[4 + w] = s2; }
    __syncthreads();
    s  = red[0] + red[1] + red[2] + red[3];
    s2 = red[4] + red[5] + red[6] + red[7];
    float mean = s / W;
    float var  = s2 / W - mean * mean;
    float rstd = rsqrtf(var + 1e-5f);
    u16* y = Y + (size_t)row * W;
    for (int i = threadIdx.x; i < W; i += 256)
        y[i] = f2bf((x[i] - mean) * rstd * g[i] + b[i]);
}

// ---------------- RoPE on Q (in place, bf16) --------------------------------
__global__ void rope_q_kernel(u16* __restrict__ Q) {
    int idx = blockIdx.x * 256 + threadIdx.x;       // NROWS*24*32
    int j = idx & 31; int t = idx >> 5; int h = t % NHEADS; int row = t / NHEADS;
    int s = row & (S_LEN - 1);
    float freq = __expf(-(float)j * (9.210340371976184f / 64.f)); // 10000^(-j/64)
    float ang = (float)s * freq;
    float c = cosf(ang), si = sinf(ang);
    u16* p = Q + (size_t)row * DMODEL + h * 128 + 64;
    float x1 = bf2f(p[j]), x2 = bf2f(p[j + 32]);
    p[j]      = f2bf(x1 * c - x2 * si);
    p[j + 32] = f2bf(x2 * c + x1 * si);
}

// ---------------- RoPE on K_rope (from fp32 ckv -> bf16 kr) -----------------
__global__ void rope_k_kernel(const float* __restrict__ ckv, u16* __restrict__ kr) {
    int idx = blockIdx.x * 256 + threadIdx.x;       // NROWS*32
    int j = idx & 31; int row = idx >> 5;
    int s = row & (S_LEN - 1);
    float freq = __expf(-(float)j * (9.210340371976184f / 64.f));
    float ang = (float)s * freq;
    float c = cosf(ang), si = sinf(ang);
    const float* src = ckv + (size_t)row * CKV_W + KVPROJ;
    float x1 = src[j], x2 = src[j + 32];
    kr[(size_t)row * 64 + j]      = f2bf(x1 * c - x2 * si);
    kr[(size_t)row * 64 + j + 32] = f2bf(x2 * c + x1 * si);
}

// ---------------- pack K: Kp[bh][s][128] = nope | roped rope ----------------
__global__ __launch_bounds__(256) void pack_k(const u16* __restrict__ KVb,
                                              const u16* __restrict__ kr,
                                              u16* __restrict__ Kp) {
    int bh = blockIdx.y, bb = bh / NHEADS, h = bh % NHEADS;
    int s0 = blockIdx.x * 64;
    int t = threadIdx.x;
    size_t base = (size_t)bb * S_LEN;
#pragma unroll
    for (int it = 0; it < 4; ++it) {
        int j = it * 256 + t;
        int r = j >> 4, cb = (j & 15) * 8;
        int s = s0 + r;
        uint4 v;
        if (cb < 64) v = *(const uint4*)&KVb[(base + s) * UKV_N + h * 192 + cb];
        else         v = *(const uint4*)&kr[(base + s) * 64 + (cb - 64)];
        *(uint4*)&Kp[((size_t)bh * S_LEN + s) * 128 + cb] = v;
    }
}

// ---------------- pack V transposed: Vt[bh][d][s] ---------------------------
__global__ __launch_bounds__(256) void pack_v(const u16* __restrict__ KVb,
                                              u16* __restrict__ Vt) {
    __shared__ u16 tile[64][136];
    int bh = blockIdx.y, bb = bh / NHEADS, h = bh % NHEADS;
    int s0 = blockIdx.x * 64;
    int t = threadIdx.x;
    size_t base = (size_t)bb * S_LEN;
#pragma unroll
    for (int it = 0; it < 4; ++it) {
        int j = it * 256 + t;
        int r = j >> 4, cb = (j & 15) * 8;
        *(uint4*)&tile[r][cb] = *(const uint4*)&KVb[(base + s0 + r) * UKV_N + h * 192 + 64 + cb];
    }
    __syncthreads();
#pragma unroll
    for (int it = 0; it < 4; ++it) {
        int j = it * 256 + t;
        int d = j >> 3, sb = (j & 7) * 8;
        u16 tmp[8];
#pragma unroll
        for (int e = 0; e < 8; ++e) tmp[e] = tile[sb + e][d];
        *(uint4*)&Vt[((size_t)bh * 128 + d) * S_LEN + s0 + sb] = *(uint4*)tmp;
    }
}

// ---------------- GEMM: 128x128 tile, BK=32, double-buffered + swizzled -----
// LDS rows are 64B; staging pre-swizzles source k-chunk by row-bit3 (XOR 32B),
// reads XOR the same -> fragment ds_read_b128 is ~2-way (free).
template<bool OUT_BF16>
__global__ __launch_bounds__(256) void gemm_nt(const u16* __restrict__ A,
                                               const u16* __restrict__ B,
                                               void* __restrict__ Cv,
                                               int M, int N, int K) {
    __shared__ u16 a_lds[2][128][32];
    __shared__ u16 b_lds[2][128][32];
    int m0 = blockIdx.y * 128, n0 = blockIdx.x * 128;
    int tid = threadIdx.x, lane = tid & 63, w = tid >> 6;
    int wm = w >> 1, wn = w & 1;
    int srow = lane >> 2;
    int kx = (lane >> 4) & 2;                    // (srow&8) ? 2 : 0
    int scol = ((lane & 3) ^ kx) * 8;            // pre-swizzled source col (elems)
    int r0 = w * 32 + srow, r1 = w * 32 + 16 + srow;
    const u16* A0 = A + (size_t)(m0 + r0) * K + scol;
    const u16* A1 = A + (size_t)(m0 + r1) * K + scol;
    int bn0 = n0 + r0; if (bn0 >= N) bn0 = N - 1;
    int bn1 = n0 + r1; if (bn1 >= N) bn1 = N - 1;
    const u16* B0 = B + (size_t)bn0 * K + scol;
    const u16* B1 = B + (size_t)bn1 * K + scol;
    char* aB = (char*)&a_lds[0][0][0];
    char* bB = (char*)&b_lds[0][0][0];
    int d0 = w * 2048, d1 = w * 2048 + 1024;     // dest byte offsets (wave-uniform)
    int cb = ((lane >> 4) * 16) ^ ((lane & 8) << 2);  // read col byte, swizzled

    f32x4 acc[4][4] = {};
    // prologue: stage kb=0 into buf 0
    async16(A0, (u16*)(aB + d0)); async16(A1, (u16*)(aB + d1));
    async16(B0, (u16*)(bB + d0)); async16(B1, (u16*)(bB + d1));
    __syncthreads();
    int buf = 0;
    for (int kb = 0; kb < K; kb += 32) {
        if (kb + 32 < K) {
            int ob = (buf ^ 1) * 8192;
            async16(A0 + kb + 32, (u16*)(aB + ob + d0));
            async16(A1 + kb + 32, (u16*)(aB + ob + d1));
            async16(B0 + kb + 32, (u16*)(bB + ob + d0));
            async16(B1 + kb + 32, (u16*)(bB + ob + d1));
        }
        const char* ab = aB + buf * 8192;
        const char* bb = bB + buf * 8192;
        short8 af[4], bf[4];
#pragma unroll
        for (int i = 0; i < 4; ++i) {
            af[i] = *(const short8*)(ab + (wm * 64 + i * 16 + (lane & 15)) * 64 + cb);
            bf[i] = *(const short8*)(bb + (wn * 64 + i * 16 + (lane & 15)) * 64 + cb);
        }
#pragma unroll
        for (int i = 0; i < 4; ++i)
#pragma unroll
            for (int j = 0; j < 4; ++j)
                acc[i][j] = __builtin_amdgcn_mfma_f32_16x16x32_bf16(af[i], bf[j], acc[i][j], 0, 0, 0);
        __syncthreads();
        buf ^= 1;
    }
#pragma unroll
    for (int i = 0; i < 4; ++i) {
        int row = m0 + wm * 64 + i * 16 + ((lane >> 4) << 2);
#pragma unroll
        for (int j = 0; j < 4; ++j) {
            int col = n0 + wn * 64 + j * 16 + (lane & 15);
            if (col < N) {
#pragma unroll
                for (int r = 0; r < 4; ++r) {
                    if (OUT_BF16) ((u16*)Cv)[(size_t)(row + r) * N + col] = f2bf(acc[i][j][r]);
                    else          ((float*)Cv)[(size_t)(row + r) * N + col] = acc[i][j][r];
                }
            }
        }
    }
}

// ---------------- Flash attention (double-buffered K/V) ---------------------
// grid: (S/64, B*H). block 256 (4 waves, 16 q-rows each).
__global__ __launch_bounds__(256) void attn_kernel(const u16* __restrict__ Qb,
                                                   const u16* __restrict__ Kp,
                                                   const u16* __restrict__ Vt,
                                                   u16* __restrict__ AO) {
    __shared__ u16 k_lds[2][64][128];
    __shared__ u16 v_lds[2][128][64];
    __shared__ u16 p_lds[4][16][72];
    int qx = (int)gridDim.x - 1 - (int)blockIdx.x;   // longest blocks first
    int q0 = qx * 64;
    int bh = blockIdx.y; int bb = bh / NHEADS, h = bh % NHEADS;
    int tid = threadIdx.x, lane = tid & 63, w = tid >> 6;
    size_t base = (size_t)bb * S_LEN;
    size_t bhS = (size_t)bh * S_LEN;

    // Q fragments (registers) — Q already pre-scaled via W_uq
    short8 qf[4];
    {
        int qrow = q0 + w * 16 + (lane & 15);
        const u16* qp = Qb + (base + qrow) * DMODEL + h * 128 + ((lane >> 4) * 8);
#pragma unroll
        for (int ks = 0; ks < 4; ++ks) qf[ks] = *(const short8*)(qp + ks * 32);
    }

    const char* Kbyte = (const char*)Kp;
    const char* Vbyte = (const char*)Vt;
    char* kB = (char*)&k_lds[0][0][0];
    char* vB = (char*)&v_lds[0][0][0];
    size_t ksrc[4], vsrc[4];
    int kd[4];
#pragma unroll
    for (int is = 0; is < 4; ++is) {
        int j = is * 256 + tid;
        int r = j >> 4;
        int cbs = ((j & 15) * 16) ^ ((r & 7) << 4);
        ksrc[is] = (bhS + r) * 256 + cbs;
        int d = j >> 3;
        int kbs = (((j & 7) ^ (d & 7)) * 16);
        vsrc[is] = ((size_t)bh * 128 + d) * (S_LEN * 2) + kbs;
        kd[is] = (is * 256 + w * 64) * 16;
    }

    f32x4 acc_o[8] = {};
    float m_run[4], l_run[4];
#pragma unroll
    for (int r = 0; r < 4; ++r) { m_run[r] = -1e30f; l_run[r] = 0.f; }

    int ntiles = qx + 1;
    // prologue: stage tile 0 into buf 0
#pragma unroll
    for (int is = 0; is < 4; ++is) async16((const u16*)(Kbyte + ksrc[is]), (u16*)(kB + kd[is]));
#pragma unroll
    for (int is = 0; is < 4; ++is) async16((const u16*)(Vbyte + vsrc[is]), (u16*)(vB + kd[is]));
    __syncthreads();
    int buf = 0;

    for (int t = 0; t < ntiles; ++t) {
        if (t + 1 < ntiles) {
            size_t kv1 = (size_t)(t + 1) * 64;
            int ob = (buf ^ 1) * 16384;
#pragma unroll
            for (int is = 0; is < 4; ++is)
                async16((const u16*)(Kbyte + ksrc[is] + kv1 * 256), (u16*)(kB + ob + kd[is]));
#pragma unroll
            for (int is = 0; is < 4; ++is)
                async16((const u16*)(Vbyte + vsrc[is] + kv1 * 2), (u16*)(vB + ob + kd[is]));
        }
        const char* kcur = kB + buf * 16384;
        const char* vcur = vB + buf * 16384;

        // QK^T: 16x64 scores per wave (swizzled k reads)
        f32x4 sc[4];
        __builtin_amdgcn_s_setprio(1);
#pragma unroll
        for (int nb = 0; nb < 4; ++nb) {
            f32x4 a = {};
            int row = nb * 16 + (lane & 15);
            const char* kb_ = kcur + row * 256;
            int x = (row & 7) << 4;
#pragma unroll
            for (int ks = 0; ks < 4; ++ks) {
                short8 kf = *(const short8*)(kb_ + ((ks * 64 + (lane >> 4) * 16) ^ x));
                a = __builtin_amdgcn_mfma_f32_16x16x32_bf16(qf[ks], kf, a, 0, 0, 0);
            }
            sc[nb] = a;
        }
        __builtin_amdgcn_s_setprio(0);

        if (t == qx) {     // only the diagonal tile needs masking
            int kv0 = t * 64;
            int qg = q0 + w * 16 + ((lane >> 4) << 2);
#pragma unroll
            for (int nb = 0; nb < 4; ++nb) {
                int kc = kv0 + nb * 16 + (lane & 15);
#pragma unroll
                for (int r = 0; r < 4; ++r)
                    if (kc > qg + r) sc[nb][r] = -1e30f;
            }
        }
        float rmax[4];
#pragma unroll
        for (int r = 0; r < 4; ++r)
            rmax[r] = fmaxf(fmaxf(sc[0][r], sc[1][r]), fmaxf(sc[2][r], sc[3][r]));
#pragma unroll
        for (int off = 1; off < 16; off <<= 1)
#pragma unroll
            for (int r = 0; r < 4; ++r) rmax[r] = fmaxf(rmax[r], __shfl_xor(rmax[r], off));

        float mnew[4], fac[4], rsum[4];
#pragma unroll
        for (int r = 0; r < 4; ++r) {
            mnew[r] = fmaxf(m_run[r], rmax[r]);
            fac[r] = __expf(m_run[r] - mnew[r]);
            rsum[r] = 0.f;
        }
#pragma unroll
        for (int nb = 0; nb < 4; ++nb)
#pragma unroll
            for (int r = 0; r < 4; ++r) {
                float p = __expf(sc[nb][r] - mnew[r]);
                sc[nb][r] = p; rsum[r] += p;
            }
#pragma unroll
        for (int off = 1; off < 16; off <<= 1)
#pragma unroll
            for (int r = 0; r < 4; ++r) rsum[r] += __shfl_xor(rsum[r], off);
#pragma unroll
        for (int r = 0; r < 4; ++r) {
            l_run[r] = l_run[r] * fac[r] + rsum[r];
            m_run[r] = mnew[r];
        }
#pragma unroll
        for (int db = 0; db < 8; ++db)
#pragma unroll
            for (int r = 0; r < 4; ++r) acc_o[db][r] *= fac[r];

        // P -> per-wave LDS (bf16), then PV with swizzled v reads
#pragma unroll
        for (int nb = 0; nb < 4; ++nb)
#pragma unroll
            for (int r = 0; r < 4; ++r)
                p_lds[w][((lane >> 4) << 2) + r][nb * 16 + (lane & 15)] = f2bf(sc[nb][r]);
        __builtin_amdgcn_sched_barrier(0);
        __builtin_amdgcn_s_setprio(1);
#pragma unroll
        for (int ks = 0; ks < 2; ++ks) {
            short8 pf = *(const short8*)&p_lds[w][lane & 15][ks * 32 + (lane >> 4) * 8];
#pragma unroll
            for (int db = 0; db < 8; ++db) {
                int row = db * 16 + (lane & 15);
                const char* vb_ = vcur + row * 128;
                short8 vf = *(const short8*)(vb_ + ((ks * 64 + (lane >> 4) * 16) ^ ((row & 7) << 4)));
                acc_o[db] = __builtin_amdgcn_mfma_f32_16x16x32_bf16(pf, vf, acc_o[db], 0, 0, 0);
            }
        }
        __builtin_amdgcn_s_setprio(0);
        __syncthreads();
        buf ^= 1;
    }

    int orow = q0 + w * 16 + ((lane >> 4) << 2);
#pragma unroll
    for (int db = 0; db < 8; ++db)
#pragma unroll
        for (int r = 0; r < 4; ++r) {
            float o = acc_o[db][r] / l_run[r];
            AO[(base + orow + r) * DMODEL + h * 128 + db * 16 + (lane & 15)] = f2bf(o);
        }
}

// ---------------------------------------------------------------------------
extern "C" void kernel_launch(void* const* d_in, const int* in_sizes, int n_in,
                              void* d_out, int out_size, void* d_ws, size_t ws_size,
                              hipStream_t stream) {
    (void)in_sizes; (void)n_in; (void)out_size; (void)ws_size;
    const float* x      = (const float*)d_in[0];
    const float* W_dq   = (const float*)d_in[1];
    const float* W_uq   = (const float*)d_in[2];
    const float* q_ln_w = (const float*)d_in[3];
    const float* q_ln_b = (const float*)d_in[4];
    const float* W_dkv  = (const float*)d_in[5];
    const float* W_ukv  = (const float*)d_in[6];
    const float* kv_ln_w= (const float*)d_in[7];
    const float* kv_ln_b= (const float*)d_in[8];
    const float* W_o    = (const float*)d_in[9];

    float* out = (float*)d_out;
    float* ckv = out + (size_t)NROWS * DMODEL;   // output #2 region

    char* ws = (char*)d_ws;
    const size_t OFF_WDQT  = 0;
    const size_t OFF_WUQT  = 9437184;
    const size_t OFF_WDKVT = 18874368;
    const size_t OFF_WUKVT = 31850496;
    const size_t OFF_WO    = 50724864;
    const size_t OFF_XB    = 69599232;
    const size_t OFF_QB    = 94765056;
    const size_t OFF_KVB   = 119930880;
    const size_t OFF_KR    = 157679616;
    const size_t OFF_SLABA = 158203904;  // t0 fp32, later ao bf16
    const size_t OFF_SLABB = 183369728;  // cq bf16, later kvl bf16
    const size_t OFF_KP    = 0;          // over Wdq_t/Wuq_t/Wdkv_t (dead), 25.2MB
    const size_t OFF_VT    = OFF_XB;     // over xb (dead), 25.2MB

    u16* Wdq_t  = (u16*)(ws + OFF_WDQT);
    u16* Wuq_t  = (u16*)(ws + OFF_WUQT);
    u16* Wdkv_t = (u16*)(ws + OFF_WDKVT);
    u16* Wukv_t = (u16*)(ws + OFF_WUKVT);
    u16* Wo_b   = (u16*)(ws + OFF_WO);
    u16* xb     = (u16*)(ws + OFF_XB);
    u16* qb     = (u16*)(ws + OFF_QB);
    u16* KVb    = (u16*)(ws + OFF_KVB);
    u16* kr     = (u16*)(ws + OFF_KR);
    float* t0   = (float*)(ws + OFF_SLABA);
    u16* ao     = (u16*)(ws + OFF_SLABA);
    u16* cq     = (u16*)(ws + OFF_SLABB);
    u16* kvl    = (u16*)(ws + OFF_SLABB);
    u16* Kp     = (u16*)(ws + OFF_KP);
    u16* Vt     = (u16*)(ws + OFF_VT);

    const float SCALE = 0.08838834764831845f;    // 1/sqrt(128), folded into W_uq

    // weight prep
    transpose_bf16<<<dim3(QPROJ / 32, DMODEL / 32), 256, 0, stream>>>(W_dq,  Wdq_t,  DMODEL, QPROJ, 1.0f);
    transpose_bf16<<<dim3(DMODEL / 32, QPROJ / 32), 256, 0, stream>>>(W_uq,  Wuq_t,  QPROJ, DMODEL, SCALE);
    transpose_bf16<<<dim3(CKV_W / 32, DMODEL / 32), 256, 0, stream>>>(W_dkv, Wdkv_t, DMODEL, CKV_W, 1.0f);
    transpose_bf16<<<dim3(UKV_N / 32, KVPROJ / 32), 256, 0, stream>>>(W_ukv, Wukv_t, KVPROJ, UKV_N, 1.0f);
    conv_bf16<<<9216, 256, 0, stream>>>(W_o, Wo_b, DMODEL * DMODEL);
    conv_bf16<<<12288, 256, 0, stream>>>(x, xb, NROWS * DMODEL);

    // q path
    gemm_nt<false><<<dim3(QPROJ / 128, NROWS / 128), 256, 0, stream>>>(xb, Wdq_t, t0, NROWS, QPROJ, DMODEL);
    ln_kernel<<<NROWS, 256, 0, stream>>>(t0, QPROJ, q_ln_w, q_ln_b, cq, QPROJ);
    gemm_nt<true><<<dim3(DMODEL / 128, NROWS / 128), 256, 0, stream>>>(cq, Wuq_t, qb, NROWS, DMODEL, QPROJ);
    rope_q_kernel<<<12288, 256, 0, stream>>>(qb);

    // kv path
    gemm_nt<false><<<dim3((CKV_W + 127) / 128, NROWS / 128), 256, 0, stream>>>(xb, Wdkv_t, ckv, NROWS, CKV_W, DMODEL);
    ln_kernel<<<NROWS, 256, 0, stream>>>(ckv, CKV_W, kv_ln_w, kv_ln_b, kvl, KVPROJ);
    rope_k_kernel<<<512, 256, 0, stream>>>(ckv, kr);
    gemm_nt<true><<<dim3(UKV_N / 128, NROWS / 128), 256, 0, stream>>>(kvl, Wukv_t, KVb, NROWS, UKV_N, KVPROJ);

    // pack K/V for attention (Wdq_t/Wuq_t/Wdkv_t and xb are dead now)
    pack_k<<<dim3(S_LEN / 64, 2 * NHEADS), 256, 0, stream>>>(KVb, kr, Kp);
    pack_v<<<dim3(S_LEN / 64, 2 * NHEADS), 256, 0, stream>>>(KVb, Vt);

    // attention
    attn_kernel<<<dim3(S_LEN / 64, 2 * NHEADS), 256, 0, stream>>>(qb, Kp, Vt, ao);

    // output projection
    gemm_nt<false><<<dim3(DMODEL / 128, NROWS / 128), 256, 0, stream>>>(ao, Wo_b, out, NROWS, DMODEL, DMODEL);
}

// Round 5
// 702.320 us; speedup vs baseline: 1.7609x; 1.0565x over previous
//
#include <hip/hip_runtime.h>

typedef unsigned short u16;
typedef __attribute__((ext_vector_type(8))) short short8;
typedef __attribute__((ext_vector_type(4))) float f32x4;

#define NROWS   4096     // B*S
#define S_LEN   2048
#define NHEADS  24
#define DMODEL  3072
#define QPROJ   1536
#define KVPROJ  2048
#define CKV_W   2112     // KVPROJ + 64 rope
#define UKV_N   4608     // DMODEL + 24*64

__device__ __forceinline__ float bf2f(u16 v) {
    unsigned u = ((unsigned)v) << 16; float f; __builtin_memcpy(&f, &u, 4); return f;
}
__device__ __forceinline__ u16 f2bf(float f) {
    unsigned u; __builtin_memcpy(&u, &f, 4);
    u = (u + 0x7FFFu + ((u >> 16) & 1u)) >> 16; return (u16)u;
}
__device__ __forceinline__ void async16(const u16* g, u16* l) {
    __builtin_amdgcn_global_load_lds((const __attribute__((address_space(1))) unsigned int*)g,
                                     (__attribute__((address_space(3))) unsigned int*)l,
                                     16, 0, 0);
}

// ---------------- elementwise convert fp32 -> bf16 (vectorized) -------------
__global__ void conv_bf16(const float* __restrict__ X, u16* __restrict__ Y, int n) {
    int i = (blockIdx.x * 256 + threadIdx.x) * 4;
    if (i >= n) return;
    float4 v = *(const float4*)(X + i);
    Y[i+0] = f2bf(v.x); Y[i+1] = f2bf(v.y); Y[i+2] = f2bf(v.z); Y[i+3] = f2bf(v.w);
}

// ---------------- transpose + convert + scale: W (K x N) -> WT (N x K) bf16 -
__global__ void transpose_bf16(const float* __restrict__ W, u16* __restrict__ WT,
                               int K, int N, float scale) {
    __shared__ float t[32][33];
    int nb = blockIdx.x * 32, kb = blockIdx.y * 32;
    int c = threadIdx.x & 31, rq = threadIdx.x >> 5;
#pragma unroll
    for (int i = 0; i < 4; ++i) {
        int r = rq * 4 + i;
        t[r][c] = W[(size_t)(kb + r) * N + nb + c];
    }
    __syncthreads();
#pragma unroll
    for (int i = 0; i < 4; ++i) {
        int r = rq * 4 + i;
        WT[(size_t)(nb + r) * K + kb + c] = f2bf(t[c][r] * scale);
    }
}

// ---------------- LayerNorm (fp32 in, bf16 out) -----------------------------
__global__ __launch_bounds__(256) void ln_kernel(const float* __restrict__ X, int ldx,
                                                 const float* __restrict__ g,
                                                 const float* __restrict__ b,
                                                 u16* __restrict__ Y, int W) {
    int row = blockIdx.x;
    const float* x = X + (size_t)row * ldx;
    float s = 0.f, s2 = 0.f;
    for (int i = threadIdx.x; i < W; i += 256) { float v = x[i]; s += v; s2 += v * v; }
#pragma unroll
    for (int off = 32; off >= 1; off >>= 1) { s += __shfl_xor(s, off); s2 += __shfl_xor(s2, off); }
    __shared__ float red[8];
    int w = threadIdx.x >> 6;
    if ((threadIdx.x & 63) == 0) { red[w] = s; red[4 + w] = s2; }
    __syncthreads();
    s  = red[0] + red[1] + red[2] + red[3];
    s2 = red[4] + red[5] + red[6] + red[7];
    float mean = s / W;
    float var  = s2 / W - mean * mean;
    float rstd = rsqrtf(var + 1e-5f);
    u16* y = Y + (size_t)row * W;
    for (int i = threadIdx.x; i < W; i += 256)
        y[i] = f2bf((x[i] - mean) * rstd * g[i] + b[i]);
}

// ---------------- RoPE on Q (in place, bf16) --------------------------------
__global__ void rope_q_kernel(u16* __restrict__ Q) {
    int idx = blockIdx.x * 256 + threadIdx.x;       // NROWS*24*32
    int j = idx & 31; int t = idx >> 5; int h = t % NHEADS; int row = t / NHEADS;
    int s = row & (S_LEN - 1);
    float freq = __expf(-(float)j * (9.210340371976184f / 64.f)); // 10000^(-j/64)
    float ang = (float)s * freq;
    float c = cosf(ang), si = sinf(ang);
    u16* p = Q + (size_t)row * DMODEL + h * 128 + 64;
    float x1 = bf2f(p[j]), x2 = bf2f(p[j + 32]);
    p[j]      = f2bf(x1 * c - x2 * si);
    p[j + 32] = f2bf(x2 * c + x1 * si);
}

// ---------------- RoPE on K_rope (from fp32 ckv -> bf16 kr) -----------------
__global__ void rope_k_kernel(const float* __restrict__ ckv, u16* __restrict__ kr) {
    int idx = blockIdx.x * 256 + threadIdx.x;       // NROWS*32
    int j = idx & 31; int row = idx >> 5;
    int s = row & (S_LEN - 1);
    float freq = __expf(-(float)j * (9.210340371976184f / 64.f));
    float ang = (float)s * freq;
    float c = cosf(ang), si = sinf(ang);
    const float* src = ckv + (size_t)row * CKV_W + KVPROJ;
    float x1 = src[j], x2 = src[j + 32];
    kr[(size_t)row * 64 + j]      = f2bf(x1 * c - x2 * si);
    kr[(size_t)row * 64 + j + 32] = f2bf(x2 * c + x1 * si);
}

// ---------------- pack K: Kp[bh][s][128] = nope | roped rope ----------------
__global__ __launch_bounds__(256) void pack_k(const u16* __restrict__ KVb,
                                              const u16* __restrict__ kr,
                                              u16* __restrict__ Kp) {
    int bh = blockIdx.y, bb = bh / NHEADS, h = bh % NHEADS;
    int s0 = blockIdx.x * 64;
    int t = threadIdx.x;
    size_t base = (size_t)bb * S_LEN;
#pragma unroll
    for (int it = 0; it < 4; ++it) {
        int j = it * 256 + t;
        int r = j >> 4, cb = (j & 15) * 8;
        int s = s0 + r;
        uint4 v;
        if (cb < 64) v = *(const uint4*)&KVb[(base + s) * UKV_N + h * 192 + cb];
        else         v = *(const uint4*)&kr[(base + s) * 64 + (cb - 64)];
        *(uint4*)&Kp[((size_t)bh * S_LEN + s) * 128 + cb] = v;
    }
}

// ---------------- pack V transposed: Vt[bh][d][s] ---------------------------
__global__ __launch_bounds__(256) void pack_v(const u16* __restrict__ KVb,
                                              u16* __restrict__ Vt) {
    __shared__ u16 tile[64][136];
    int bh = blockIdx.y, bb = bh / NHEADS, h = bh % NHEADS;
    int s0 = blockIdx.x * 64;
    int t = threadIdx.x;
    size_t base = (size_t)bb * S_LEN;
#pragma unroll
    for (int it = 0; it < 4; ++it) {
        int j = it * 256 + t;
        int r = j >> 4, cb = (j & 15) * 8;
        *(uint4*)&tile[r][cb] = *(const uint4*)&KVb[(base + s0 + r) * UKV_N + h * 192 + 64 + cb];
    }
    __syncthreads();
#pragma unroll
    for (int it = 0; it < 4; ++it) {
        int j = it * 256 + t;
        int d = j >> 3, sb = (j & 7) * 8;
        u16 tmp[8];
#pragma unroll
        for (int e = 0; e < 8; ++e) tmp[e] = tile[sb + e][d];
        *(uint4*)&Vt[((size_t)bh * 128 + d) * S_LEN + s0 + sb] = *(uint4*)tmp;
    }
}

// ---------------- GEMM: 128x128 tile, BK=32, double-buffered + swizzled -----
template<bool OUT_BF16>
__global__ __launch_bounds__(256) void gemm_nt(const u16* __restrict__ A,
                                               const u16* __restrict__ B,
                                               void* __restrict__ Cv,
                                               int M, int N, int K) {
    __shared__ u16 a_lds[2][128][32];
    __shared__ u16 b_lds[2][128][32];
    int m0 = blockIdx.y * 128, n0 = blockIdx.x * 128;
    int tid = threadIdx.x, lane = tid & 63, w = tid >> 6;
    int wm = w >> 1, wn = w & 1;
    int srow = lane >> 2;
    int kx = (lane >> 4) & 2;                    // (srow&8) ? 2 : 0
    int scol = ((lane & 3) ^ kx) * 8;            // pre-swizzled source col (elems)
    int r0 = w * 32 + srow, r1 = w * 32 + 16 + srow;
    const u16* A0 = A + (size_t)(m0 + r0) * K + scol;
    const u16* A1 = A + (size_t)(m0 + r1) * K + scol;
    int bn0 = n0 + r0; if (bn0 >= N) bn0 = N - 1;
    int bn1 = n0 + r1; if (bn1 >= N) bn1 = N - 1;
    const u16* B0 = B + (size_t)bn0 * K + scol;
    const u16* B1 = B + (size_t)bn1 * K + scol;
    char* aB = (char*)&a_lds[0][0][0];
    char* bB = (char*)&b_lds[0][0][0];
    int d0 = w * 2048, d1 = w * 2048 + 1024;     // dest byte offsets (wave-uniform)
    int cb = ((lane >> 4) * 16) ^ ((lane & 8) << 2);  // read col byte, swizzled

    f32x4 acc[4][4] = {};
    async16(A0, (u16*)(aB + d0)); async16(A1, (u16*)(aB + d1));
    async16(B0, (u16*)(bB + d0)); async16(B1, (u16*)(bB + d1));
    __syncthreads();
    int buf = 0;
    for (int kb = 0; kb < K; kb += 32) {
        if (kb + 32 < K) {
            int ob = (buf ^ 1) * 8192;
            async16(A0 + kb + 32, (u16*)(aB + ob + d0));
            async16(A1 + kb + 32, (u16*)(aB + ob + d1));
            async16(B0 + kb + 32, (u16*)(bB + ob + d0));
            async16(B1 + kb + 32, (u16*)(bB + ob + d1));
        }
        const char* ab = aB + buf * 8192;
        const char* bb = bB + buf * 8192;
        short8 af[4], bf[4];
#pragma unroll
        for (int i = 0; i < 4; ++i) {
            af[i] = *(const short8*)(ab + (wm * 64 + i * 16 + (lane & 15)) * 64 + cb);
            bf[i] = *(const short8*)(bb + (wn * 64 + i * 16 + (lane & 15)) * 64 + cb);
        }
#pragma unroll
        for (int i = 0; i < 4; ++i)
#pragma unroll
            for (int j = 0; j < 4; ++j)
                acc[i][j] = __builtin_amdgcn_mfma_f32_16x16x32_bf16(af[i], bf[j], acc[i][j], 0, 0, 0);
        __syncthreads();
        buf ^= 1;
    }
#pragma unroll
    for (int i = 0; i < 4; ++i) {
        int row = m0 + wm * 64 + i * 16 + ((lane >> 4) << 2);
#pragma unroll
        for (int j = 0; j < 4; ++j) {
            int col = n0 + wn * 64 + j * 16 + (lane & 15);
            if (col < N) {
#pragma unroll
                for (int r = 0; r < 4; ++r) {
                    if (OUT_BF16) ((u16*)Cv)[(size_t)(row + r) * N + col] = f2bf(acc[i][j][r]);
                    else          ((float*)Cv)[(size_t)(row + r) * N + col] = acc[i][j][r];
                }
            }
        }
    }
}

// ---------------- Flash attention: QBLK=128, 8 waves, single-buffered -------
// grid: (S/128, B*H). block 512 (8 waves, 16 q-rows each). K/V tiles shared
// by 2x the q-rows of the old version; TLP (16 waves/CU) hides staging latency.
__global__ __launch_bounds__(512) void attn_kernel(const u16* __restrict__ Qb,
                                                   const u16* __restrict__ Kp,
                                                   const u16* __restrict__ Vt,
                                                   u16* __restrict__ AO) {
    __shared__ u16 k_lds[64][128];     // 16 KB
    __shared__ u16 v_lds[128][64];     // 16 KB
    __shared__ u16 p_lds[8][16][72];   // 18.4 KB
    int qxb = (int)gridDim.x - 1 - (int)blockIdx.x;   // longest blocks first
    int q0 = qxb * 128;
    int bh = blockIdx.y; int bb = bh / NHEADS, h = bh % NHEADS;
    int tid = threadIdx.x, lane = tid & 63, w = tid >> 6;   // w in 0..7
    size_t base = (size_t)bb * S_LEN;
    size_t bhS = (size_t)bh * S_LEN;

    // Q fragments (registers) — Q already pre-scaled via W_uq
    short8 qf[4];
    {
        int qrow = q0 + w * 16 + (lane & 15);
        const u16* qp = Qb + (base + qrow) * DMODEL + h * 128 + ((lane >> 4) * 8);
#pragma unroll
        for (int ks = 0; ks < 4; ++ks) qf[ks] = *(const short8*)(qp + ks * 32);
    }

    const char* Kbyte = (const char*)Kp;
    const char* Vbyte = (const char*)Vt;
    char* kB = (char*)&k_lds[0][0];
    char* vB = (char*)&v_lds[0][0];
    size_t ksrc[2], vsrc[2];
    int kd[2];
#pragma unroll
    for (int is = 0; is < 2; ++is) {
        int j = is * 512 + tid;                  // chunk 0..1023
        int r = j >> 4;                          // k row (16 chunks/row)
        int cbs = ((j & 15) * 16) ^ ((r & 7) << 4);
        ksrc[is] = (bhS + r) * 256 + cbs;
        int d = j >> 3;                          // v row (8 chunks/row)
        int kbs = (((j & 7) ^ (d & 7)) * 16);
        vsrc[is] = ((size_t)bh * 128 + d) * (S_LEN * 2) + kbs;
        kd[is] = (is * 512 + w * 64) * 16;       // wave-uniform dest base
    }

    f32x4 acc_o[8] = {};
    float m_run[4], l_run[4];
#pragma unroll
    for (int r = 0; r < 4; ++r) { m_run[r] = -1e30f; l_run[r] = 0.f; }

    int ntiles = 2 * qxb + 2;
    int wave_nt = ((q0 + w * 16 + 15) >> 6) + 1;     // tiles this wave needs

    for (int t = 0; t < ntiles; ++t) {
        size_t kv0 = (size_t)t * 64;
#pragma unroll
        for (int is = 0; is < 2; ++is)
            async16((const u16*)(Kbyte + ksrc[is] + kv0 * 256), (u16*)(kB + kd[is]));
#pragma unroll
        for (int is = 0; is < 2; ++is)
            async16((const u16*)(Vbyte + vsrc[is] + kv0 * 2), (u16*)(vB + kd[is]));
        __syncthreads();

        if (t < wave_nt) {
            // QK^T: 16x64 scores per wave (swizzled k reads)
            f32x4 sc[4];
            __builtin_amdgcn_s_setprio(1);
#pragma unroll
            for (int nb = 0; nb < 4; ++nb) {
                f32x4 a = {};
                int row = nb * 16 + (lane & 15);
                const char* kb_ = kB + row * 256;
                int x = (row & 7) << 4;
#pragma unroll
                for (int ks = 0; ks < 4; ++ks) {
                    short8 kf = *(const short8*)(kb_ + ((ks * 64 + (lane >> 4) * 16) ^ x));
                    a = __builtin_amdgcn_mfma_f32_16x16x32_bf16(qf[ks], kf, a, 0, 0, 0);
                }
                sc[nb] = a;
            }
            __builtin_amdgcn_s_setprio(0);

            if (t + 1 == wave_nt) {     // this wave's diagonal tile
                int kvb = t * 64;
                int qg = q0 + w * 16 + ((lane >> 4) << 2);
#pragma unroll
                for (int nb = 0; nb < 4; ++nb) {
                    int kc = kvb + nb * 16 + (lane & 15);
#pragma unroll
                    for (int r = 0; r < 4; ++r)
                        if (kc > qg + r) sc[nb][r] = -1e30f;
                }
            }
            float rmax[4];
#pragma unroll
            for (int r = 0; r < 4; ++r)
                rmax[r] = fmaxf(fmaxf(sc[0][r], sc[1][r]), fmaxf(sc[2][r], sc[3][r]));
#pragma unroll
            for (int off = 1; off < 16; off <<= 1)
#pragma unroll
                for (int r = 0; r < 4; ++r) rmax[r] = fmaxf(rmax[r], __shfl_xor(rmax[r], off));

            float mnew[4], fac[4], rsum[4];
#pragma unroll
            for (int r = 0; r < 4; ++r) {
                mnew[r] = fmaxf(m_run[r], rmax[r]);
                fac[r] = __expf(m_run[r] - mnew[r]);
                rsum[r] = 0.f;
            }
#pragma unroll
            for (int nb = 0; nb < 4; ++nb)
#pragma unroll
                for (int r = 0; r < 4; ++r) {
                    float p = __expf(sc[nb][r] - mnew[r]);
                    sc[nb][r] = p; rsum[r] += p;
                }
#pragma unroll
            for (int off = 1; off < 16; off <<= 1)
#pragma unroll
                for (int r = 0; r < 4; ++r) rsum[r] += __shfl_xor(rsum[r], off);
#pragma unroll
            for (int r = 0; r < 4; ++r) {
                l_run[r] = l_run[r] * fac[r] + rsum[r];
                m_run[r] = mnew[r];
            }
#pragma unroll
            for (int db = 0; db < 8; ++db)
#pragma unroll
                for (int r = 0; r < 4; ++r) acc_o[db][r] *= fac[r];

            // P -> per-wave LDS (bf16), then PV with swizzled v reads
#pragma unroll
            for (int nb = 0; nb < 4; ++nb)
#pragma unroll
                for (int r = 0; r < 4; ++r)
                    p_lds[w][((lane >> 4) << 2) + r][nb * 16 + (lane & 15)] = f2bf(sc[nb][r]);
            __builtin_amdgcn_sched_barrier(0);
            __builtin_amdgcn_s_setprio(1);
#pragma unroll
            for (int ks = 0; ks < 2; ++ks) {
                short8 pf = *(const short8*)&p_lds[w][lane & 15][ks * 32 + (lane >> 4) * 8];
#pragma unroll
                for (int db = 0; db < 8; ++db) {
                    int row = db * 16 + (lane & 15);
                    const char* vb_ = vB + row * 128;
                    short8 vf = *(const short8*)(vb_ + ((ks * 64 + (lane >> 4) * 16) ^ ((row & 7) << 4)));
                    acc_o[db] = __builtin_amdgcn_mfma_f32_16x16x32_bf16(pf, vf, acc_o[db], 0, 0, 0);
                }
            }
            __builtin_amdgcn_s_setprio(0);
        }
        __syncthreads();
    }

    int orow = q0 + w * 16 + ((lane >> 4) << 2);
#pragma unroll
    for (int db = 0; db < 8; ++db)
#pragma unroll
        for (int r = 0; r < 4; ++r) {
            float o = acc_o[db][r] / l_run[r];
            AO[(base + orow + r) * DMODEL + h * 128 + db * 16 + (lane & 15)] = f2bf(o);
        }
}

// ---------------------------------------------------------------------------
extern "C" void kernel_launch(void* const* d_in, const int* in_sizes, int n_in,
                              void* d_out, int out_size, void* d_ws, size_t ws_size,
                              hipStream_t stream) {
    (void)in_sizes; (void)n_in; (void)out_size; (void)ws_size;
    const float* x      = (const float*)d_in[0];
    const float* W_dq   = (const float*)d_in[1];
    const float* W_uq   = (const float*)d_in[2];
    const float* q_ln_w = (const float*)d_in[3];
    const float* q_ln_b = (const float*)d_in[4];
    const float* W_dkv  = (const float*)d_in[5];
    const float* W_ukv  = (const float*)d_in[6];
    const float* kv_ln_w= (const float*)d_in[7];
    const float* kv_ln_b= (const float*)d_in[8];
    const float* W_o    = (const float*)d_in[9];

    float* out = (float*)d_out;
    float* ckv = out + (size_t)NROWS * DMODEL;   // output #2 region

    char* ws = (char*)d_ws;
    const size_t OFF_WDQT  = 0;
    const size_t OFF_WUQT  = 9437184;
    const size_t OFF_WDKVT = 18874368;
    const size_t OFF_WUKVT = 31850496;
    const size_t OFF_WO    = 50724864;
    const size_t OFF_XB    = 69599232;
    const size_t OFF_QB    = 94765056;
    const size_t OFF_KVB   = 119930880;
    const size_t OFF_KR    = 157679616;
    const size_t OFF_SLABA = 158203904;  // t0 fp32, later ao bf16
    const size_t OFF_SLABB = 183369728;  // cq bf16, later kvl bf16
    const size_t OFF_KP    = 0;          // over Wdq_t/Wuq_t/Wdkv_t (dead), 25.2MB
    const size_t OFF_VT    = OFF_XB;     // over xb (dead), 25.2MB

    u16* Wdq_t  = (u16*)(ws + OFF_WDQT);
    u16* Wuq_t  = (u16*)(ws + OFF_WUQT);
    u16* Wdkv_t = (u16*)(ws + OFF_WDKVT);
    u16* Wukv_t = (u16*)(ws + OFF_WUKVT);
    u16* Wo_b   = (u16*)(ws + OFF_WO);
    u16* xb     = (u16*)(ws + OFF_XB);
    u16* qb     = (u16*)(ws + OFF_QB);
    u16* KVb    = (u16*)(ws + OFF_KVB);
    u16* kr     = (u16*)(ws + OFF_KR);
    float* t0   = (float*)(ws + OFF_SLABA);
    u16* ao     = (u16*)(ws + OFF_SLABA);
    u16* cq     = (u16*)(ws + OFF_SLABB);
    u16* kvl    = (u16*)(ws + OFF_SLABB);
    u16* Kp     = (u16*)(ws + OFF_KP);
    u16* Vt     = (u16*)(ws + OFF_VT);

    const float SCALE = 0.08838834764831845f;    // 1/sqrt(128), folded into W_uq

    // weight prep
    transpose_bf16<<<dim3(QPROJ / 32, DMODEL / 32), 256, 0, stream>>>(W_dq,  Wdq_t,  DMODEL, QPROJ, 1.0f);
    transpose_bf16<<<dim3(DMODEL / 32, QPROJ / 32), 256, 0, stream>>>(W_uq,  Wuq_t,  QPROJ, DMODEL, SCALE);
    transpose_bf16<<<dim3(CKV_W / 32, DMODEL / 32), 256, 0, stream>>>(W_dkv, Wdkv_t, DMODEL, CKV_W, 1.0f);
    transpose_bf16<<<dim3(UKV_N / 32, KVPROJ / 32), 256, 0, stream>>>(W_ukv, Wukv_t, KVPROJ, UKV_N, 1.0f);
    conv_bf16<<<9216, 256, 0, stream>>>(W_o, Wo_b, DMODEL * DMODEL);
    conv_bf16<<<12288, 256, 0, stream>>>(x, xb, NROWS * DMODEL);

    // q path
    gemm_nt<false><<<dim3(QPROJ / 128, NROWS / 128), 256, 0, stream>>>(xb, Wdq_t, t0, NROWS, QPROJ, DMODEL);
    ln_kernel<<<NROWS, 256, 0, stream>>>(t0, QPROJ, q_ln_w, q_ln_b, cq, QPROJ);
    gemm_nt<true><<<dim3(DMODEL / 128, NROWS / 128), 256, 0, stream>>>(cq, Wuq_t, qb, NROWS, DMODEL, QPROJ);
    rope_q_kernel<<<12288, 256, 0, stream>>>(qb);

    // kv path
    gemm_nt<false><<<dim3((CKV_W + 127) / 128, NROWS / 128), 256, 0, stream>>>(xb, Wdkv_t, ckv, NROWS, CKV_W, DMODEL);
    ln_kernel<<<NROWS, 256, 0, stream>>>(ckv, CKV_W, kv_ln_w, kv_ln_b, kvl, KVPROJ);
    rope_k_kernel<<<512, 256, 0, stream>>>(ckv, kr);
    gemm_nt<true><<<dim3(UKV_N / 128, NROWS / 128), 256, 0, stream>>>(kvl, Wukv_t, KVb, NROWS, UKV_N, KVPROJ);

    // pack K/V for attention (Wdq_t/Wuq_t/Wdkv_t and xb are dead now)
    pack_k<<<dim3(S_LEN / 64, 2 * NHEADS), 256, 0, stream>>>(KVb, kr, Kp);
    pack_v<<<dim3(S_LEN / 64, 2 * NHEADS), 256, 0, stream>>>(KVb, Vt);

    // attention
    attn_kernel<<<dim3(S_LEN / 128, 2 * NHEADS), 512, 0, stream>>>(qb, Kp, Vt, ao);

    // output projection
    gemm_nt<false><<<dim3(DMODEL / 128, NROWS / 128), 256, 0, stream>>>(ao, Wo_b, out, NROWS, DMODEL, DMODEL);
}

// Round 6
// 672.361 us; speedup vs baseline: 1.8394x; 1.0446x over previous
//
#include <hip/hip_runtime.h>

typedef unsigned short u16;
typedef __attribute__((ext_vector_type(8))) short short8;
typedef __attribute__((ext_vector_type(4))) float f32x4;

#define NROWS   4096     // B*S
#define S_LEN   2048
#define NHEADS  24
#define DMODEL  3072
#define QPROJ   1536
#define KVPROJ  2048
#define CKV_W   2112     // KVPROJ + 64 rope
#define UKV_N   4608     // DMODEL + 24*64

__device__ __forceinline__ float bf2f(u16 v) {
    unsigned u = ((unsigned)v) << 16; float f; __builtin_memcpy(&f, &u, 4); return f;
}
__device__ __forceinline__ u16 f2bf(float f) {
    unsigned u; __builtin_memcpy(&u, &f, 4);
    u = (u + 0x7FFFu + ((u >> 16) & 1u)) >> 16; return (u16)u;
}
__device__ __forceinline__ void async16(const u16* g, u16* l) {
    __builtin_amdgcn_global_load_lds((const __attribute__((address_space(1))) unsigned int*)g,
                                     (__attribute__((address_space(3))) unsigned int*)l,
                                     16, 0, 0);
}

// ---------------- elementwise convert fp32 -> bf16 (vectorized) -------------
__global__ void conv_bf16(const float* __restrict__ X, u16* __restrict__ Y, int n) {
    int i = (blockIdx.x * 256 + threadIdx.x) * 4;
    if (i >= n) return;
    float4 v = *(const float4*)(X + i);
    Y[i+0] = f2bf(v.x); Y[i+1] = f2bf(v.y); Y[i+2] = f2bf(v.z); Y[i+3] = f2bf(v.w);
}

// ---------------- transpose + convert + scale: W (K x N) -> WT (N x K) bf16 -
__global__ void transpose_bf16(const float* __restrict__ W, u16* __restrict__ WT,
                               int K, int N, float scale) {
    __shared__ float t[32][33];
    int nb = blockIdx.x * 32, kb = blockIdx.y * 32;
    int c = threadIdx.x & 31, rq = threadIdx.x >> 5;
#pragma unroll
    for (int i = 0; i < 4; ++i) {
        int r = rq * 4 + i;
        t[r][c] = W[(size_t)(kb + r) * N + nb + c];
    }
    __syncthreads();
#pragma unroll
    for (int i = 0; i < 4; ++i) {
        int r = rq * 4 + i;
        WT[(size_t)(nb + r) * K + kb + c] = f2bf(t[c][r] * scale);
    }
}

// ---------------- LayerNorm (fp32 in, bf16 out) -----------------------------
__global__ __launch_bounds__(256) void ln_kernel(const float* __restrict__ X, int ldx,
                                                 const float* __restrict__ g,
                                                 const float* __restrict__ b,
                                                 u16* __restrict__ Y, int W) {
    int row = blockIdx.x;
    const float* x = X + (size_t)row * ldx;
    float s = 0.f, s2 = 0.f;
    for (int i = threadIdx.x; i < W; i += 256) { float v = x[i]; s += v; s2 += v * v; }
#pragma unroll
    for (int off = 32; off >= 1; off >>= 1) { s += __shfl_xor(s, off); s2 += __shfl_xor(s2, off); }
    __shared__ float red[8];
    int w = threadIdx.x >> 6;
    if ((threadIdx.x & 63) == 0) { red[w] = s; red[4 + w] = s2; }
    __syncthreads();
    s  = red[0] + red[1] + red[2] + red[3];
    s2 = red[4] + red[5] + red[6] + red[7];
    float mean = s / W;
    float var  = s2 / W - mean * mean;
    float rstd = rsqrtf(var + 1e-5f);
    u16* y = Y + (size_t)row * W;
    for (int i = threadIdx.x; i < W; i += 256)
        y[i] = f2bf((x[i] - mean) * rstd * g[i] + b[i]);
}

// ---------------- RoPE on Q (in place, bf16) --------------------------------
__global__ void rope_q_kernel(u16* __restrict__ Q) {
    int idx = blockIdx.x * 256 + threadIdx.x;       // NROWS*24*32
    int j = idx & 31; int t = idx >> 5; int h = t % NHEADS; int row = t / NHEADS;
    int s = row & (S_LEN - 1);
    float freq = __expf(-(float)j * (9.210340371976184f / 64.f)); // 10000^(-j/64)
    float ang = (float)s * freq;
    float c = cosf(ang), si = sinf(ang);
    u16* p = Q + (size_t)row * DMODEL + h * 128 + 64;
    float x1 = bf2f(p[j]), x2 = bf2f(p[j + 32]);
    p[j]      = f2bf(x1 * c - x2 * si);
    p[j + 32] = f2bf(x2 * c + x1 * si);
}

// ---------------- RoPE on K_rope (from fp32 ckv -> bf16 kr) -----------------
__global__ void rope_k_kernel(const float* __restrict__ ckv, u16* __restrict__ kr) {
    int idx = blockIdx.x * 256 + threadIdx.x;       // NROWS*32
    int j = idx & 31; int row = idx >> 5;
    int s = row & (S_LEN - 1);
    float freq = __expf(-(float)j * (9.210340371976184f / 64.f));
    float ang = (float)s * freq;
    float c = cosf(ang), si = sinf(ang);
    const float* src = ckv + (size_t)row * CKV_W + KVPROJ;
    float x1 = src[j], x2 = src[j + 32];
    kr[(size_t)row * 64 + j]      = f2bf(x1 * c - x2 * si);
    kr[(size_t)row * 64 + j + 32] = f2bf(x2 * c + x1 * si);
}

// ---------------- pack K: Kp[bh][s][128] = nope | roped rope ----------------
__global__ __launch_bounds__(256) void pack_k(const u16* __restrict__ KVb,
                                              const u16* __restrict__ kr,
                                              u16* __restrict__ Kp) {
    int bh = blockIdx.y, bb = bh / NHEADS, h = bh % NHEADS;
    int s0 = blockIdx.x * 64;
    int t = threadIdx.x;
    size_t base = (size_t)bb * S_LEN;
#pragma unroll
    for (int it = 0; it < 4; ++it) {
        int j = it * 256 + t;
        int r = j >> 4, cb = (j & 15) * 8;
        int s = s0 + r;
        uint4 v;
        if (cb < 64) v = *(const uint4*)&KVb[(base + s) * UKV_N + h * 192 + cb];
        else         v = *(const uint4*)&kr[(base + s) * 64 + (cb - 64)];
        *(uint4*)&Kp[((size_t)bh * S_LEN + s) * 128 + cb] = v;
    }
}

// ---------------- pack V transposed: Vt[bh][d][s] ---------------------------
__global__ __launch_bounds__(256) void pack_v(const u16* __restrict__ KVb,
                                              u16* __restrict__ Vt) {
    __shared__ u16 tile[64][136];
    int bh = blockIdx.y, bb = bh / NHEADS, h = bh % NHEADS;
    int s0 = blockIdx.x * 64;
    int t = threadIdx.x;
    size_t base = (size_t)bb * S_LEN;
#pragma unroll
    for (int it = 0; it < 4; ++it) {
        int j = it * 256 + t;
        int r = j >> 4, cb = (j & 15) * 8;
        *(uint4*)&tile[r][cb] = *(const uint4*)&KVb[(base + s0 + r) * UKV_N + h * 192 + 64 + cb];
    }
    __syncthreads();
#pragma unroll
    for (int it = 0; it < 4; ++it) {
        int j = it * 256 + t;
        int d = j >> 3, sb = (j & 7) * 8;
        u16 tmp[8];
#pragma unroll
        for (int e = 0; e < 8; ++e) tmp[e] = tile[sb + e][d];
        *(uint4*)&Vt[((size_t)bh * 128 + d) * S_LEN + s0 + sb] = *(uint4*)tmp;
    }
}

// ---------------- GEMM: 128x128 tile, BK=32, double-buffered + swizzled -----
template<bool OUT_BF16>
__global__ __launch_bounds__(256) void gemm_nt(const u16* __restrict__ A,
                                               const u16* __restrict__ B,
                                               void* __restrict__ Cv,
                                               int M, int N, int K) {
    __shared__ u16 a_lds[2][128][32];
    __shared__ u16 b_lds[2][128][32];
    int m0 = blockIdx.y * 128, n0 = blockIdx.x * 128;
    int tid = threadIdx.x, lane = tid & 63, w = tid >> 6;
    int wm = w >> 1, wn = w & 1;
    int srow = lane >> 2;
    int kx = (lane >> 4) & 2;                    // (srow&8) ? 2 : 0
    int scol = ((lane & 3) ^ kx) * 8;            // pre-swizzled source col (elems)
    int r0 = w * 32 + srow, r1 = w * 32 + 16 + srow;
    const u16* A0 = A + (size_t)(m0 + r0) * K + scol;
    const u16* A1 = A + (size_t)(m0 + r1) * K + scol;
    int bn0 = n0 + r0; if (bn0 >= N) bn0 = N - 1;
    int bn1 = n0 + r1; if (bn1 >= N) bn1 = N - 1;
    const u16* B0 = B + (size_t)bn0 * K + scol;
    const u16* B1 = B + (size_t)bn1 * K + scol;
    char* aB = (char*)&a_lds[0][0][0];
    char* bB = (char*)&b_lds[0][0][0];
    int d0 = w * 2048, d1 = w * 2048 + 1024;     // dest byte offsets (wave-uniform)
    int cb = ((lane >> 4) * 16) ^ ((lane & 8) << 2);  // read col byte, swizzled

    f32x4 acc[4][4] = {};
    async16(A0, (u16*)(aB + d0)); async16(A1, (u16*)(aB + d1));
    async16(B0, (u16*)(bB + d0)); async16(B1, (u16*)(bB + d1));
    __syncthreads();
    int buf = 0;
    for (int kb = 0; kb < K; kb += 32) {
        if (kb + 32 < K) {
            int ob = (buf ^ 1) * 8192;
            async16(A0 + kb + 32, (u16*)(aB + ob + d0));
            async16(A1 + kb + 32, (u16*)(aB + ob + d1));
            async16(B0 + kb + 32, (u16*)(bB + ob + d0));
            async16(B1 + kb + 32, (u16*)(bB + ob + d1));
        }
        const char* ab = aB + buf * 8192;
        const char* bb = bB + buf * 8192;
        short8 af[4], bf[4];
#pragma unroll
        for (int i = 0; i < 4; ++i) {
            af[i] = *(const short8*)(ab + (wm * 64 + i * 16 + (lane & 15)) * 64 + cb);
            bf[i] = *(const short8*)(bb + (wn * 64 + i * 16 + (lane & 15)) * 64 + cb);
        }
#pragma unroll
        for (int i = 0; i < 4; ++i)
#pragma unroll
            for (int j = 0; j < 4; ++j)
                acc[i][j] = __builtin_amdgcn_mfma_f32_16x16x32_bf16(af[i], bf[j], acc[i][j], 0, 0, 0);
        __syncthreads();
        buf ^= 1;
    }
#pragma unroll
    for (int i = 0; i < 4; ++i) {
        int row = m0 + wm * 64 + i * 16 + ((lane >> 4) << 2);
#pragma unroll
        for (int j = 0; j < 4; ++j) {
            int col = n0 + wn * 64 + j * 16 + (lane & 15);
            if (col < N) {
#pragma unroll
                for (int r = 0; r < 4; ++r) {
                    if (OUT_BF16) ((u16*)Cv)[(size_t)(row + r) * N + col] = f2bf(acc[i][j][r]);
                    else          ((float*)Cv)[(size_t)(row + r) * N + col] = acc[i][j][r];
                }
            }
        }
    }
}

// ---------------- Flash attention: paired causal blocks, XCD-clustered ------
// grid: 768 flat blocks, 256 thr (4 waves x 16 q-rows). Each block processes
// q-tiles (31-bx) then (bx) of one head -> uniform 33 tile-iterations/block.
// Head decode clusters all 16 blocks of a head onto one XCD (L2 locality).
__global__ __launch_bounds__(256) void attn_kernel(const u16* __restrict__ Qb,
                                                   const u16* __restrict__ Kp,
                                                   const u16* __restrict__ Vt,
                                                   u16* __restrict__ AO) {
    __shared__ u16 k_lds[64][128];     // 16 KB
    __shared__ u16 v_lds[128][64];     // 16 KB
    __shared__ u16 p_lds[4][16][72];   // 9.2 KB
    int bid = blockIdx.x;
    int jj = bid >> 3;
    int bh = (bid & 7) * 6 + (jj >> 4);          // all 16 blocks of a head on one XCD
    int bx = jj & 15;
    int bb = bh / NHEADS, h = bh % NHEADS;
    int tid = threadIdx.x, lane = tid & 63, w = tid >> 6;
    size_t base = (size_t)bb * S_LEN;
    size_t bhS = (size_t)bh * S_LEN;

    // staging addresses (head-dependent only; hoisted across segments)
    const char* Kbyte = (const char*)Kp;
    const char* Vbyte = (const char*)Vt;
    char* kB = (char*)&k_lds[0][0];
    char* vB = (char*)&v_lds[0][0];
    size_t ksrc[4], vsrc[4];
    int kd[4];
#pragma unroll
    for (int is = 0; is < 4; ++is) {
        int j = is * 256 + tid;
        int r = j >> 4;                          // k row (16 chunks/row)
        int cbs = ((j & 15) * 16) ^ ((r & 7) << 4);
        ksrc[is] = (bhS + r) * 256 + cbs;
        int d = j >> 3;                          // v row (8 chunks/row)
        int kbs = (((j & 7) ^ (d & 7)) * 16);
        vsrc[is] = ((size_t)bh * 128 + d) * (S_LEN * 2) + kbs;
        kd[is] = (is * 256 + w * 64) * 16;       // wave-uniform dest base
    }

    for (int seg = 0; seg < 2; ++seg) {
        int qx = seg == 0 ? (31 - bx) : bx;      // long segment first
        int q0 = qx * 64;

        // Q fragments (registers) — Q already pre-scaled via W_uq
        short8 qf[4];
        {
            int qrow = q0 + w * 16 + (lane & 15);
            const u16* qp = Qb + (base + qrow) * DMODEL + h * 128 + ((lane >> 4) * 8);
#pragma unroll
            for (int ks = 0; ks < 4; ++ks) qf[ks] = *(const short8*)(qp + ks * 32);
        }

        f32x4 acc_o[8] = {};
        float m_run[4], l_run[4];
#pragma unroll
        for (int r = 0; r < 4; ++r) { m_run[r] = -1e30f; l_run[r] = 0.f; }

        int ntiles = qx + 1;
        for (int t = 0; t < ntiles; ++t) {
            size_t kv0 = (size_t)t * 64;
#pragma unroll
            for (int is = 0; is < 4; ++is)
                async16((const u16*)(Kbyte + ksrc[is] + kv0 * 256), (u16*)(kB + kd[is]));
#pragma unroll
            for (int is = 0; is < 4; ++is)
                async16((const u16*)(Vbyte + vsrc[is] + kv0 * 2), (u16*)(vB + kd[is]));
            __syncthreads();

            // QK^T: 16x64 scores per wave (swizzled k reads)
            f32x4 sc[4];
            __builtin_amdgcn_s_setprio(1);
#pragma unroll
            for (int nb = 0; nb < 4; ++nb) {
                f32x4 a = {};
                int row = nb * 16 + (lane & 15);
                const char* kb_ = kB + row * 256;
                int x = (row & 7) << 4;
#pragma unroll
                for (int ks = 0; ks < 4; ++ks) {
                    short8 kf = *(const short8*)(kb_ + ((ks * 64 + (lane >> 4) * 16) ^ x));
                    a = __builtin_amdgcn_mfma_f32_16x16x32_bf16(qf[ks], kf, a, 0, 0, 0);
                }
                sc[nb] = a;
            }
            __builtin_amdgcn_s_setprio(0);

            if (t == qx) {     // diagonal tile: causal mask
                int kvb = t * 64;
                int qg = q0 + w * 16 + ((lane >> 4) << 2);
#pragma unroll
                for (int nb = 0; nb < 4; ++nb) {
                    int kc = kvb + nb * 16 + (lane & 15);
#pragma unroll
                    for (int r = 0; r < 4; ++r)
                        if (kc > qg + r) sc[nb][r] = -1e30f;
                }
            }
            float rmax[4];
#pragma unroll
            for (int r = 0; r < 4; ++r)
                rmax[r] = fmaxf(fmaxf(sc[0][r], sc[1][r]), fmaxf(sc[2][r], sc[3][r]));
#pragma unroll
            for (int off = 1; off < 16; off <<= 1)
#pragma unroll
                for (int r = 0; r < 4; ++r) rmax[r] = fmaxf(rmax[r], __shfl_xor(rmax[r], off));

            // defer-max (exact, THR=0): rescale only if a row max grew
            bool ok = (rmax[0] <= m_run[0]) & (rmax[1] <= m_run[1]) &
                      (rmax[2] <= m_run[2]) & (rmax[3] <= m_run[3]);
            if (!__all(ok)) {
                float fac[4];
#pragma unroll
                for (int r = 0; r < 4; ++r) {
                    float mnew = fmaxf(m_run[r], rmax[r]);
                    fac[r] = __expf(m_run[r] - mnew);
                    m_run[r] = mnew;
                    l_run[r] *= fac[r];
                }
#pragma unroll
                for (int db = 0; db < 8; ++db)
#pragma unroll
                    for (int r = 0; r < 4; ++r) acc_o[db][r] *= fac[r];
            }
            float rsum[4] = {0.f, 0.f, 0.f, 0.f};
#pragma unroll
            for (int nb = 0; nb < 4; ++nb)
#pragma unroll
                for (int r = 0; r < 4; ++r) {
                    float p = __expf(sc[nb][r] - m_run[r]);
                    sc[nb][r] = p; rsum[r] += p;
                }
#pragma unroll
            for (int off = 1; off < 16; off <<= 1)
#pragma unroll
                for (int r = 0; r < 4; ++r) rsum[r] += __shfl_xor(rsum[r], off);
#pragma unroll
            for (int r = 0; r < 4; ++r) l_run[r] += rsum[r];

            // P -> per-wave LDS (bf16), then PV with swizzled v reads
#pragma unroll
            for (int nb = 0; nb < 4; ++nb)
#pragma unroll
                for (int r = 0; r < 4; ++r)
                    p_lds[w][((lane >> 4) << 2) + r][nb * 16 + (lane & 15)] = f2bf(sc[nb][r]);
            __builtin_amdgcn_sched_barrier(0);
            __builtin_amdgcn_s_setprio(1);
#pragma unroll
            for (int ks = 0; ks < 2; ++ks) {
                short8 pf = *(const short8*)&p_lds[w][lane & 15][ks * 32 + (lane >> 4) * 8];
#pragma unroll
                for (int db = 0; db < 8; ++db) {
                    int row = db * 16 + (lane & 15);
                    const char* vb_ = vB + row * 128;
                    short8 vf = *(const short8*)(vb_ + ((ks * 64 + (lane >> 4) * 16) ^ ((row & 7) << 4)));
                    acc_o[db] = __builtin_amdgcn_mfma_f32_16x16x32_bf16(pf, vf, acc_o[db], 0, 0, 0);
                }
            }
            __builtin_amdgcn_s_setprio(0);
            __syncthreads();
        }

        int orow = q0 + w * 16 + ((lane >> 4) << 2);
#pragma unroll
        for (int db = 0; db < 8; ++db)
#pragma unroll
            for (int r = 0; r < 4; ++r) {
                float o = acc_o[db][r] / l_run[r];
                AO[(base + orow + r) * DMODEL + h * 128 + db * 16 + (lane & 15)] = f2bf(o);
            }
    }
}

// ---------------------------------------------------------------------------
extern "C" void kernel_launch(void* const* d_in, const int* in_sizes, int n_in,
                              void* d_out, int out_size, void* d_ws, size_t ws_size,
                              hipStream_t stream) {
    (void)in_sizes; (void)n_in; (void)out_size; (void)ws_size;
    const float* x      = (const float*)d_in[0];
    const float* W_dq   = (const float*)d_in[1];
    const float* W_uq   = (const float*)d_in[2];
    const float* q_ln_w = (const float*)d_in[3];
    const float* q_ln_b = (const float*)d_in[4];
    const float* W_dkv  = (const float*)d_in[5];
    const float* W_ukv  = (const float*)d_in[6];
    const float* kv_ln_w= (const float*)d_in[7];
    const float* kv_ln_b= (const float*)d_in[8];
    const float* W_o    = (const float*)d_in[9];

    float* out = (float*)d_out;
    float* ckv = out + (size_t)NROWS * DMODEL;   // output #2 region

    char* ws = (char*)d_ws;
    const size_t OFF_WDQT  = 0;
    const size_t OFF_WUQT  = 9437184;
    const size_t OFF_WDKVT = 18874368;
    const size_t OFF_WUKVT = 31850496;
    const size_t OFF_WO    = 50724864;
    const size_t OFF_XB    = 69599232;
    const size_t OFF_QB    = 94765056;
    const size_t OFF_KVB   = 119930880;
    const size_t OFF_KR    = 157679616;
    const size_t OFF_SLABA = 158203904;  // t0 fp32, later ao bf16
    const size_t OFF_SLABB = 183369728;  // cq bf16, later kvl bf16
    const size_t OFF_KP    = 0;          // over Wdq_t/Wuq_t/Wdkv_t (dead), 25.2MB
    const size_t OFF_VT    = OFF_XB;     // over xb (dead), 25.2MB

    u16* Wdq_t  = (u16*)(ws + OFF_WDQT);
    u16* Wuq_t  = (u16*)(ws + OFF_WUQT);
    u16* Wdkv_t = (u16*)(ws + OFF_WDKVT);
    u16* Wukv_t = (u16*)(ws + OFF_WUKVT);
    u16* Wo_b   = (u16*)(ws + OFF_WO);
    u16* xb     = (u16*)(ws + OFF_XB);
    u16* qb     = (u16*)(ws + OFF_QB);
    u16* KVb    = (u16*)(ws + OFF_KVB);
    u16* kr     = (u16*)(ws + OFF_KR);
    float* t0   = (float*)(ws + OFF_SLABA);
    u16* ao     = (u16*)(ws + OFF_SLABA);
    u16* cq     = (u16*)(ws + OFF_SLABB);
    u16* kvl    = (u16*)(ws + OFF_SLABB);
    u16* Kp     = (u16*)(ws + OFF_KP);
    u16* Vt     = (u16*)(ws + OFF_VT);

    const float SCALE = 0.08838834764831845f;    // 1/sqrt(128), folded into W_uq

    // weight prep
    transpose_bf16<<<dim3(QPROJ / 32, DMODEL / 32), 256, 0, stream>>>(W_dq,  Wdq_t,  DMODEL, QPROJ, 1.0f);
    transpose_bf16<<<dim3(DMODEL / 32, QPROJ / 32), 256, 0, stream>>>(W_uq,  Wuq_t,  QPROJ, DMODEL, SCALE);
    transpose_bf16<<<dim3(CKV_W / 32, DMODEL / 32), 256, 0, stream>>>(W_dkv, Wdkv_t, DMODEL, CKV_W, 1.0f);
    transpose_bf16<<<dim3(UKV_N / 32, KVPROJ / 32), 256, 0, stream>>>(W_ukv, Wukv_t, KVPROJ, UKV_N, 1.0f);
    conv_bf16<<<9216, 256, 0, stream>>>(W_o, Wo_b, DMODEL * DMODEL);
    conv_bf16<<<12288, 256, 0, stream>>>(x, xb, NROWS * DMODEL);

    // q path
    gemm_nt<false><<<dim3(QPROJ / 128, NROWS / 128), 256, 0, stream>>>(xb, Wdq_t, t0, NROWS, QPROJ, DMODEL);
    ln_kernel<<<NROWS, 256, 0, stream>>>(t0, QPROJ, q_ln_w, q_ln_b, cq, QPROJ);
    gemm_nt<true><<<dim3(DMODEL / 128, NROWS / 128), 256, 0, stream>>>(cq, Wuq_t, qb, NROWS, DMODEL, QPROJ);
    rope_q_kernel<<<12288, 256, 0, stream>>>(qb);

    // kv path
    gemm_nt<false><<<dim3((CKV_W + 127) / 128, NROWS / 128), 256, 0, stream>>>(xb, Wdkv_t, ckv, NROWS, CKV_W, DMODEL);
    ln_kernel<<<NROWS, 256, 0, stream>>>(ckv, CKV_W, kv_ln_w, kv_ln_b, kvl, KVPROJ);
    rope_k_kernel<<<512, 256, 0, stream>>>(ckv, kr);
    gemm_nt<true><<<dim3(UKV_N / 128, NROWS / 128), 256, 0, stream>>>(kvl, Wukv_t, KVb, NROWS, UKV_N, KVPROJ);

    // pack K/V for attention (Wdq_t/Wuq_t/Wdkv_t and xb are dead now)
    pack_k<<<dim3(S_LEN / 64, 2 * NHEADS), 256, 0, stream>>>(KVb, kr, Kp);
    pack_v<<<dim3(S_LEN / 64, 2 * NHEADS), 256, 0, stream>>>(KVb, Vt);

    // attention (768 uniform paired blocks, XCD head-clustered)
    attn_kernel<<<768, 256, 0, stream>>>(qb, Kp, Vt, ao);

    // output projection
    gemm_nt<false><<<dim3(DMODEL / 128, NROWS / 128), 256, 0, stream>>>(ao, Wo_b, out, NROWS, DMODEL, DMODEL);
}